// Round 2
// baseline (1283.293 us; speedup 1.0000x reference)
//
#include <hip/hip_runtime.h>

#define S_LEN 2048
#define NH 16
#define DH 64
#define DM 1024
#define NB 2
#define BS 4096  // NB*S_LEN

typedef __attribute__((ext_vector_type(4))) float f32x4;
typedef __attribute__((ext_vector_type(8))) short bfrag;  // 8 bf16 in 4 VGPRs

__device__ __forceinline__ unsigned short f2bf(float f) {
    unsigned u = __builtin_bit_cast(unsigned, f);
    u += 0x7FFFu + ((u >> 16) & 1u);
    return (unsigned short)(u >> 16);
}

// ---------------- generic B^T GEMM: C[m,n] = sum_k A[m,k]*Bt[n,k] ----------------
// AF/BF: 1 = input is fp32 (convert to bf16 during LDS staging), 0 = bf16.
// EPI 0: write bf16 to (b,h,s,d)   [projection Q,K]
// EPI 1: write bf16 to (b,h,d,s)   [projection V, transposed for PV]
// EPI 2: write fp32 [M][N]         [output projection]
template <int EPI, int AF, int BF>
__global__ __launch_bounds__(256) void gemm_bt(const void* __restrict__ Av,
                                               const void* __restrict__ Bv,
                                               void* __restrict__ Out, int M, int N, int K) {
    const int tid = threadIdx.x;
    const int lane = tid & 63;
    const int w = tid >> 6, wr = w >> 1, wc = w & 1;
    const int m0 = blockIdx.y * 128;
    const int n0 = blockIdx.x * 128;

    __shared__ unsigned short sA[128 * 64];
    __shared__ unsigned short sB[128 * 64];

    f32x4 acc[4][4];
#pragma unroll
    for (int i = 0; i < 4; ++i)
#pragma unroll
        for (int j = 0; j < 4; ++j) acc[i][j] = (f32x4){0.f, 0.f, 0.f, 0.f};

    for (int k0 = 0; k0 < K; k0 += 64) {
        // stage A
        if constexpr (AF) {
            const float* A = (const float*)Av;
#pragma unroll
            for (int i = 0; i < 8; ++i) {
                int c = i * 256 + tid;  // 2048 chunks of 4 fp32
                int row = c >> 4, col4 = c & 15;
                float4 v = *reinterpret_cast<const float4*>(A + (size_t)(m0 + row) * K + k0 +
                                                            col4 * 4);
                ushort4 o;
                o.x = f2bf(v.x); o.y = f2bf(v.y); o.z = f2bf(v.z); o.w = f2bf(v.w);
                *reinterpret_cast<ushort4*>(sA + row * 64 + ((col4 * 4) ^ ((row & 7) * 8))) = o;
            }
        } else {
            const unsigned short* A = (const unsigned short*)Av;
#pragma unroll
            for (int i = 0; i < 4; ++i) {
                int c = i * 256 + tid;  // 1024 chunks of 8 bf16
                int row = c >> 3, col8 = c & 7;
                *reinterpret_cast<int4*>(sA + row * 64 + ((col8 * 8) ^ ((row & 7) * 8))) =
                    *reinterpret_cast<const int4*>(A + (size_t)(m0 + row) * K + k0 + col8 * 8);
            }
        }
        // stage B
        if constexpr (BF) {
            const float* B = (const float*)Bv;
#pragma unroll
            for (int i = 0; i < 8; ++i) {
                int c = i * 256 + tid;
                int row = c >> 4, col4 = c & 15;
                float4 v = *reinterpret_cast<const float4*>(B + (size_t)(n0 + row) * K + k0 +
                                                            col4 * 4);
                ushort4 o;
                o.x = f2bf(v.x); o.y = f2bf(v.y); o.z = f2bf(v.z); o.w = f2bf(v.w);
                *reinterpret_cast<ushort4*>(sB + row * 64 + ((col4 * 4) ^ ((row & 7) * 8))) = o;
            }
        } else {
            const unsigned short* B = (const unsigned short*)Bv;
#pragma unroll
            for (int i = 0; i < 4; ++i) {
                int c = i * 256 + tid;
                int row = c >> 3, col8 = c & 7;
                *reinterpret_cast<int4*>(sB + row * 64 + ((col8 * 8) ^ ((row & 7) * 8))) =
                    *reinterpret_cast<const int4*>(B + (size_t)(n0 + row) * K + k0 + col8 * 8);
            }
        }
        __syncthreads();
#pragma unroll
        for (int kk = 0; kk < 2; ++kk) {
            bfrag a[4], b[4];
#pragma unroll
            for (int f = 0; f < 4; ++f) {
                int ra = wr * 64 + f * 16 + (lane & 15);
                a[f] = *reinterpret_cast<const bfrag*>(
                    sA + ra * 64 + ((kk * 32 + (lane >> 4) * 8) ^ ((ra & 7) * 8)));
                int rb = wc * 64 + f * 16 + (lane & 15);
                b[f] = *reinterpret_cast<const bfrag*>(
                    sB + rb * 64 + ((kk * 32 + (lane >> 4) * 8) ^ ((rb & 7) * 8)));
            }
#pragma unroll
            for (int fm = 0; fm < 4; ++fm)
#pragma unroll
                for (int fn = 0; fn < 4; ++fn)
                    acc[fm][fn] =
                        __builtin_amdgcn_mfma_f32_16x16x32_bf16(a[fm], b[fn], acc[fm][fn], 0, 0, 0);
        }
        __syncthreads();
    }

    // epilogue: C/D layout col=lane&15, row=(lane>>4)*4+r  [m89-verified]
    if constexpr (EPI == 1) {
#pragma unroll
        for (int fm = 0; fm < 4; ++fm)
#pragma unroll
            for (int fn = 0; fn < 4; ++fn) {
                int sbase = m0 + wr * 64 + fm * 16 + ((lane >> 4) << 2);
                int gcol = n0 + wc * 64 + fn * 16 + (lane & 15);
                int b = sbase >> 11, s = sbase & 2047, h = gcol >> 6, d = gcol & 63;
                ushort4 o;
                o.x = f2bf(acc[fm][fn][0]); o.y = f2bf(acc[fm][fn][1]);
                o.z = f2bf(acc[fm][fn][2]); o.w = f2bf(acc[fm][fn][3]);
                *reinterpret_cast<ushort4*>((unsigned short*)Out +
                                            ((size_t)(b * NH + h) * DH + d) * S_LEN + s) = o;
            }
    } else {
#pragma unroll
        for (int fm = 0; fm < 4; ++fm)
#pragma unroll
            for (int fn = 0; fn < 4; ++fn)
#pragma unroll
                for (int r = 0; r < 4; ++r) {
                    int grow = m0 + wr * 64 + fm * 16 + ((lane >> 4) << 2) + r;
                    int gcol = n0 + wc * 64 + fn * 16 + (lane & 15);
                    float v = acc[fm][fn][r];
                    if constexpr (EPI == 0) {
                        int b = grow >> 11, s = grow & 2047, h = gcol >> 6, d = gcol & 63;
                        ((unsigned short*)Out)[((size_t)(b * NH + h) * S_LEN + s) * DH + d] =
                            f2bf(v);
                    } else {
                        ((float*)Out)[(size_t)grow * N + gcol] = v;
                    }
                }
    }
}

// ---------------- fused scores + softmax + PV ----------------
// One block = one (b,h) head, one 128-row Q strip. 4 waves, wave w owns rows
// w*32..w*32+31 (row softmax reductions stay intra-wave: shfl_xor 1,2,4,8).
// Phase 1: per 128-col K-tile: S = qk^T*scale + prev, write scores, online m/l.
// Phase 2: re-read scores (L2/L3), p = exp(s-m)/l, write attn, bf16->LDS,
//          MFMA P@V into O accumulator. Write ctx bf16.
__global__ __launch_bounds__(256) void attn_fused(const unsigned short* __restrict__ qh,
                                                  const unsigned short* __restrict__ kh,
                                                  const unsigned short* __restrict__ vT,
                                                  const float* __restrict__ prev,
                                                  float* __restrict__ scores,
                                                  float* __restrict__ attn,
                                                  unsigned short* __restrict__ ctx) {
    const int z = blockIdx.z;            // b*NH + h
    const int m0 = blockIdx.x * 128;     // Q strip base
    const int tid = threadIdx.x;
    const int lane = tid & 63;
    const int w = tid >> 6;              // wave id: owns rows w*32..w*32+31

    __shared__ unsigned short sQ[128 * 64];
    __shared__ unsigned short sKV[128 * 64];   // K tile (phase 1) / V tile (phase 2)
    __shared__ unsigned short sP[128 * 128];

    const unsigned short* Qz = qh + (size_t)z * S_LEN * DH;
    const unsigned short* Kz = kh + (size_t)z * S_LEN * DH;
    const unsigned short* Vz = vT + (size_t)z * DH * S_LEN;
    const size_t zbase = (size_t)z * S_LEN * S_LEN;

    // stage Q strip once (guarded by the barrier inside the first kt iteration)
#pragma unroll
    for (int i = 0; i < 4; ++i) {
        int c = i * 256 + tid;
        int row = c >> 3, col8 = c & 7;
        *reinterpret_cast<int4*>(sQ + row * 64 + ((col8 * 8) ^ ((row & 7) * 8))) =
            *reinterpret_cast<const int4*>(Qz + (size_t)(m0 + row) * DH + col8 * 8);
    }

    float m_r[2][4], l_r[2][4];
#pragma unroll
    for (int fm = 0; fm < 2; ++fm)
#pragma unroll
        for (int r = 0; r < 4; ++r) { m_r[fm][r] = -1e30f; l_r[fm][r] = 0.f; }

    const float scale = 0.125f;  // 1/sqrt(64)

    // ---------- phase 1 ----------
    for (int kt = 0; kt < S_LEN / 128; ++kt) {
        const int n0 = kt * 128;
        __syncthreads();  // prior iter done reading sKV
#pragma unroll
        for (int i = 0; i < 4; ++i) {
            int c = i * 256 + tid;
            int row = c >> 3, col8 = c & 7;
            *reinterpret_cast<int4*>(sKV + row * 64 + ((col8 * 8) ^ ((row & 7) * 8))) =
                *reinterpret_cast<const int4*>(Kz + (size_t)(n0 + row) * DH + col8 * 8);
        }
        __syncthreads();

        f32x4 acc[2][8];
#pragma unroll
        for (int fm = 0; fm < 2; ++fm)
#pragma unroll
            for (int fn = 0; fn < 8; ++fn) acc[fm][fn] = (f32x4){0.f, 0.f, 0.f, 0.f};

#pragma unroll
        for (int kk = 0; kk < 2; ++kk) {
            bfrag a[2], b[8];
#pragma unroll
            for (int f = 0; f < 2; ++f) {
                int ra = w * 32 + f * 16 + (lane & 15);
                a[f] = *reinterpret_cast<const bfrag*>(
                    sQ + ra * 64 + ((kk * 32 + (lane >> 4) * 8) ^ ((ra & 7) * 8)));
            }
#pragma unroll
            for (int f = 0; f < 8; ++f) {
                int rb = f * 16 + (lane & 15);
                b[f] = *reinterpret_cast<const bfrag*>(
                    sKV + rb * 64 + ((kk * 32 + (lane >> 4) * 8) ^ ((rb & 7) * 8)));
            }
#pragma unroll
            for (int fm = 0; fm < 2; ++fm)
#pragma unroll
                for (int fn = 0; fn < 8; ++fn)
                    acc[fm][fn] =
                        __builtin_amdgcn_mfma_f32_16x16x32_bf16(a[fm], b[fn], acc[fm][fn], 0, 0, 0);
        }

        // scale + prev, write scores, online softmax state
#pragma unroll
        for (int fm = 0; fm < 2; ++fm) {
            const int growb = m0 + w * 32 + fm * 16 + ((lane >> 4) << 2);
#pragma unroll
            for (int fn = 0; fn < 8; ++fn) {
                const int gcol = n0 + fn * 16 + (lane & 15);
#pragma unroll
                for (int r = 0; r < 4; ++r) {
                    size_t idx = zbase + (size_t)(growb + r) * S_LEN + gcol;
                    float s = acc[fm][fn][r] * scale + prev[idx];
                    scores[idx] = s;
                    acc[fm][fn][r] = s;
                }
            }
#pragma unroll
            for (int r = 0; r < 4; ++r) {
                float pm = acc[fm][0][r];
#pragma unroll
                for (int fn = 1; fn < 8; ++fn) pm = fmaxf(pm, acc[fm][fn][r]);
                pm = fmaxf(pm, __shfl_xor(pm, 1));
                pm = fmaxf(pm, __shfl_xor(pm, 2));
                pm = fmaxf(pm, __shfl_xor(pm, 4));
                pm = fmaxf(pm, __shfl_xor(pm, 8));
                float mnew = fmaxf(m_r[fm][r], pm);
                float psum = 0.f;
#pragma unroll
                for (int fn = 0; fn < 8; ++fn) psum += __expf(acc[fm][fn][r] - mnew);
                psum += __shfl_xor(psum, 1);
                psum += __shfl_xor(psum, 2);
                psum += __shfl_xor(psum, 4);
                psum += __shfl_xor(psum, 8);
                l_r[fm][r] = l_r[fm][r] * __expf(m_r[fm][r] - mnew) + psum;
                m_r[fm][r] = mnew;
            }
        }
    }

    float inv_l[2][4];
#pragma unroll
    for (int fm = 0; fm < 2; ++fm)
#pragma unroll
        for (int r = 0; r < 4; ++r) inv_l[fm][r] = 1.0f / l_r[fm][r];

    // ---------- phase 2 ----------
    f32x4 acco[2][4];
#pragma unroll
    for (int fm = 0; fm < 2; ++fm)
#pragma unroll
        for (int fn = 0; fn < 4; ++fn) acco[fm][fn] = (f32x4){0.f, 0.f, 0.f, 0.f};

    for (int kt = 0; kt < S_LEN / 128; ++kt) {
        const int n0 = kt * 128;
        __syncthreads();  // prior iter done reading sKV/sP
        // stage V tile: vT[d=0..63][n0..n0+127] -> sKV as [64][128]
#pragma unroll
        for (int i = 0; i < 4; ++i) {
            int c = i * 256 + tid;
            int row = c >> 4, col8 = c & 15;
            *reinterpret_cast<int4*>(sKV + row * 128 + (((col8 ^ (row & 7)) << 3))) =
                *reinterpret_cast<const int4*>(Vz + (size_t)row * S_LEN + n0 + col8 * 8);
        }
        // reload scores, normalize, write attn, stage p into sP
#pragma unroll
        for (int fm = 0; fm < 2; ++fm) {
            const int prowb = w * 32 + fm * 16 + ((lane >> 4) << 2);
#pragma unroll
            for (int fn = 0; fn < 8; ++fn) {
                const int pcol = fn * 16 + (lane & 15);
#pragma unroll
                for (int r = 0; r < 4; ++r) {
                    size_t idx = zbase + (size_t)(m0 + prowb + r) * S_LEN + n0 + pcol;
                    float s = scores[idx];
                    float p = __expf(s - m_r[fm][r]) * inv_l[fm][r];
                    attn[idx] = p;
                    sP[(prowb + r) * 128 + ((((pcol >> 3) ^ ((prowb + r) & 7)) << 3)) +
                       (pcol & 7)] = f2bf(p);
                }
            }
        }
        __syncthreads();
        // O += P @ V
#pragma unroll
        for (int kk = 0; kk < 4; ++kk) {
            bfrag a[2], b[4];
#pragma unroll
            for (int f = 0; f < 2; ++f) {
                int ra = w * 32 + f * 16 + (lane & 15);
                a[f] = *reinterpret_cast<const bfrag*>(
                    sP + ra * 128 + (((kk * 4 + (lane >> 4)) ^ (ra & 7)) << 3));
            }
#pragma unroll
            for (int f = 0; f < 4; ++f) {
                int rb = f * 16 + (lane & 15);
                b[f] = *reinterpret_cast<const bfrag*>(
                    sKV + rb * 128 + (((kk * 4 + (lane >> 4)) ^ (rb & 7)) << 3));
            }
#pragma unroll
            for (int fm = 0; fm < 2; ++fm)
#pragma unroll
                for (int fn = 0; fn < 4; ++fn)
                    acco[fm][fn] =
                        __builtin_amdgcn_mfma_f32_16x16x32_bf16(a[fm], b[fn], acco[fm][fn], 0, 0, 0);
        }
    }

    // write ctx (b, s, h*DH + d) bf16
    const int b = z >> 4, h = z & 15;
#pragma unroll
    for (int fm = 0; fm < 2; ++fm)
#pragma unroll
        for (int fn = 0; fn < 4; ++fn)
#pragma unroll
            for (int r = 0; r < 4; ++r) {
                int s = m0 + w * 32 + fm * 16 + ((lane >> 4) << 2) + r;
                int d = fn * 16 + (lane & 15);
                ctx[((size_t)(b * S_LEN + s)) * DM + h * DH + d] = f2bf(acco[fm][fn][r]);
            }
}

extern "C" void kernel_launch(void* const* d_in, const int* in_sizes, int n_in, void* d_out,
                              int out_size, void* d_ws, size_t ws_size, hipStream_t stream) {
    const float* Q = (const float*)d_in[0];
    const float* K = (const float*)d_in[1];
    const float* V = (const float*)d_in[2];
    const float* prev = (const float*)d_in[3];
    const float* Wq = (const float*)d_in[4];
    const float* Wk = (const float*)d_in[5];
    const float* Wv = (const float*)d_in[6];
    const float* Wo = (const float*)d_in[7];

    float* out = (float*)d_out;
    float* attn = out + (size_t)BS * DM;
    float* scores = attn + (size_t)NB * NH * S_LEN * S_LEN;

    unsigned short* ws = (unsigned short*)d_ws;
    unsigned short* qh = ws;                      // (b,h,s,d) bf16
    unsigned short* kh = qh + (size_t)BS * DM;    // (b,h,s,d) bf16
    unsigned short* vT = kh + (size_t)BS * DM;    // (b,h,d,s) bf16
    unsigned short* ctx = vT + (size_t)BS * DM;   // (b,s,h*d) bf16

    // projections (fp32 inputs, cast fused into staging)
    dim3 gp(DM / 128, BS / 128, 1);
    gemm_bt<0, 1, 1><<<gp, 256, 0, stream>>>(Q, Wq, qh, BS, DM, DM);
    gemm_bt<0, 1, 1><<<gp, 256, 0, stream>>>(K, Wk, kh, BS, DM, DM);
    gemm_bt<1, 1, 1><<<gp, 256, 0, stream>>>(V, Wv, vT, BS, DM, DM);

    // fused scores + softmax + PV
    dim3 ga(S_LEN / 128, 1, NB * NH);
    attn_fused<<<ga, 256, 0, stream>>>(qh, kh, vT, prev, scores, attn, ctx);

    // output projection (A = ctx bf16, B = Wo fp32)
    gemm_bt<2, 0, 1><<<gp, 256, 0, stream>>>(ctx, Wo, out, BS, DM, DM);
}

// Round 3
// 824.225 us; speedup vs baseline: 1.5570x; 1.5570x over previous
//
#include <hip/hip_runtime.h>

#define S_LEN 2048
#define NH 16
#define DH 64
#define DM 1024
#define NB 2
#define BS 4096  // NB*S_LEN

typedef __attribute__((ext_vector_type(4))) float f32x4;
typedef __attribute__((ext_vector_type(8))) short bfrag;  // 8 bf16 in 4 VGPRs

__device__ __forceinline__ unsigned short f2bf(float f) {
    unsigned u = __builtin_bit_cast(unsigned, f);
    u += 0x7FFFu + ((u >> 16) & 1u);
    return (unsigned short)(u >> 16);
}

// ================= combined QKV projection =================
// z = 0/1/2 -> Q/K/V. C[m,n] = sum_k A[m,k]*W[n,k], A,W fp32 (cast in staging).
// z<2: write bf16 (b,h,s,d); z==2: write bf16 (b,h,d,s) for PV B-operand.
__global__ __launch_bounds__(256) void gemm_qkv(const float* __restrict__ Qi,
                                                const float* __restrict__ Ki,
                                                const float* __restrict__ Vi,
                                                const float* __restrict__ Wq,
                                                const float* __restrict__ Wk,
                                                const float* __restrict__ Wv,
                                                unsigned short* __restrict__ qh,
                                                unsigned short* __restrict__ kh,
                                                unsigned short* __restrict__ vT) {
    const int z = blockIdx.z;
    const float* A = (z == 0) ? Qi : (z == 1) ? Ki : Vi;
    const float* B = (z == 0) ? Wq : (z == 1) ? Wk : Wv;
    const int tid = threadIdx.x, lane = tid & 63;
    const int w = tid >> 6, wr = w >> 1, wc = w & 1;
    const int m0 = blockIdx.y * 128, n0 = blockIdx.x * 128;
    const int K = DM;

    __shared__ unsigned short sA[128 * 64];
    __shared__ unsigned short sB[128 * 64];

    f32x4 acc[4][4];
#pragma unroll
    for (int i = 0; i < 4; ++i)
#pragma unroll
        for (int j = 0; j < 4; ++j) acc[i][j] = (f32x4){0.f, 0.f, 0.f, 0.f};

    for (int k0 = 0; k0 < K; k0 += 64) {
        float4 va[8], vb[8];
#pragma unroll
        for (int i = 0; i < 8; ++i) {
            int c = i * 256 + tid;
            int row = c >> 4, col4 = c & 15;
            va[i] = *reinterpret_cast<const float4*>(A + (size_t)(m0 + row) * K + k0 + col4 * 4);
            vb[i] = *reinterpret_cast<const float4*>(B + (size_t)(n0 + row) * K + k0 + col4 * 4);
        }
#pragma unroll
        for (int i = 0; i < 8; ++i) {
            int c = i * 256 + tid;
            int row = c >> 4, col4 = c & 15;
            ushort4 oa, ob;
            oa.x = f2bf(va[i].x); oa.y = f2bf(va[i].y); oa.z = f2bf(va[i].z); oa.w = f2bf(va[i].w);
            ob.x = f2bf(vb[i].x); ob.y = f2bf(vb[i].y); ob.z = f2bf(vb[i].z); ob.w = f2bf(vb[i].w);
            *reinterpret_cast<ushort4*>(sA + row * 64 + ((col4 * 4) ^ ((row & 7) * 8))) = oa;
            *reinterpret_cast<ushort4*>(sB + row * 64 + ((col4 * 4) ^ ((row & 7) * 8))) = ob;
        }
        __syncthreads();
#pragma unroll
        for (int kk = 0; kk < 2; ++kk) {
            bfrag a[4], b[4];
#pragma unroll
            for (int f = 0; f < 4; ++f) {
                int ra = wr * 64 + f * 16 + (lane & 15);
                a[f] = *reinterpret_cast<const bfrag*>(
                    sA + ra * 64 + ((kk * 32 + (lane >> 4) * 8) ^ ((ra & 7) * 8)));
                int rb = wc * 64 + f * 16 + (lane & 15);
                b[f] = *reinterpret_cast<const bfrag*>(
                    sB + rb * 64 + ((kk * 32 + (lane >> 4) * 8) ^ ((rb & 7) * 8)));
            }
#pragma unroll
            for (int fm = 0; fm < 4; ++fm)
#pragma unroll
                for (int fn = 0; fn < 4; ++fn)
                    acc[fm][fn] =
                        __builtin_amdgcn_mfma_f32_16x16x32_bf16(a[fm], b[fn], acc[fm][fn], 0, 0, 0);
        }
        __syncthreads();
    }

    if (z == 2) {
#pragma unroll
        for (int fm = 0; fm < 4; ++fm)
#pragma unroll
            for (int fn = 0; fn < 4; ++fn) {
                int sbase = m0 + wr * 64 + fm * 16 + ((lane >> 4) << 2);
                int gcol = n0 + wc * 64 + fn * 16 + (lane & 15);
                int b = sbase >> 11, s = sbase & 2047, h = gcol >> 6, d = gcol & 63;
                ushort4 o;
                o.x = f2bf(acc[fm][fn][0]); o.y = f2bf(acc[fm][fn][1]);
                o.z = f2bf(acc[fm][fn][2]); o.w = f2bf(acc[fm][fn][3]);
                *reinterpret_cast<ushort4*>(vT + ((size_t)(b * NH + h) * DH + d) * S_LEN + s) = o;
            }
    } else {
        unsigned short* Out = (z == 0) ? qh : kh;
#pragma unroll
        for (int fm = 0; fm < 4; ++fm)
#pragma unroll
            for (int fn = 0; fn < 4; ++fn)
#pragma unroll
                for (int r = 0; r < 4; ++r) {
                    int grow = m0 + wr * 64 + fm * 16 + ((lane >> 4) << 2) + r;
                    int gcol = n0 + wc * 64 + fn * 16 + (lane & 15);
                    int b = grow >> 11, s = grow & 2047, h = gcol >> 6, d = gcol & 63;
                    Out[((size_t)(b * NH + h) * S_LEN + s) * DH + d] = f2bf(acc[fm][fn][r]);
                }
    }
}

// ================= output projection: out[m,n] = sum_k ctx[m,k]*Wo[n,k] =================
// ctx bf16, Wo fp32, out fp32.
__global__ __launch_bounds__(256) void gemm_out(const unsigned short* __restrict__ A,
                                                const float* __restrict__ B,
                                                float* __restrict__ Out) {
    const int tid = threadIdx.x, lane = tid & 63;
    const int w = tid >> 6, wr = w >> 1, wc = w & 1;
    const int m0 = blockIdx.y * 128, n0 = blockIdx.x * 128;
    const int K = DM, N = DM;

    __shared__ unsigned short sA[128 * 64];
    __shared__ unsigned short sB[128 * 64];

    f32x4 acc[4][4];
#pragma unroll
    for (int i = 0; i < 4; ++i)
#pragma unroll
        for (int j = 0; j < 4; ++j) acc[i][j] = (f32x4){0.f, 0.f, 0.f, 0.f};

    for (int k0 = 0; k0 < K; k0 += 64) {
        int4 va[4];
        float4 vb[8];
#pragma unroll
        for (int i = 0; i < 4; ++i) {
            int c = i * 256 + tid;
            int row = c >> 3, col8 = c & 7;
            va[i] = *reinterpret_cast<const int4*>(A + (size_t)(m0 + row) * K + k0 + col8 * 8);
        }
#pragma unroll
        for (int i = 0; i < 8; ++i) {
            int c = i * 256 + tid;
            int row = c >> 4, col4 = c & 15;
            vb[i] = *reinterpret_cast<const float4*>(B + (size_t)(n0 + row) * K + k0 + col4 * 4);
        }
#pragma unroll
        for (int i = 0; i < 4; ++i) {
            int c = i * 256 + tid;
            int row = c >> 3, col8 = c & 7;
            *reinterpret_cast<int4*>(sA + row * 64 + ((col8 * 8) ^ ((row & 7) * 8))) = va[i];
        }
#pragma unroll
        for (int i = 0; i < 8; ++i) {
            int c = i * 256 + tid;
            int row = c >> 4, col4 = c & 15;
            ushort4 ob;
            ob.x = f2bf(vb[i].x); ob.y = f2bf(vb[i].y); ob.z = f2bf(vb[i].z); ob.w = f2bf(vb[i].w);
            *reinterpret_cast<ushort4*>(sB + row * 64 + ((col4 * 4) ^ ((row & 7) * 8))) = ob;
        }
        __syncthreads();
#pragma unroll
        for (int kk = 0; kk < 2; ++kk) {
            bfrag a[4], b[4];
#pragma unroll
            for (int f = 0; f < 4; ++f) {
                int ra = wr * 64 + f * 16 + (lane & 15);
                a[f] = *reinterpret_cast<const bfrag*>(
                    sA + ra * 64 + ((kk * 32 + (lane >> 4) * 8) ^ ((ra & 7) * 8)));
                int rb = wc * 64 + f * 16 + (lane & 15);
                b[f] = *reinterpret_cast<const bfrag*>(
                    sB + rb * 64 + ((kk * 32 + (lane >> 4) * 8) ^ ((rb & 7) * 8)));
            }
#pragma unroll
            for (int fm = 0; fm < 4; ++fm)
#pragma unroll
                for (int fn = 0; fn < 4; ++fn)
                    acc[fm][fn] =
                        __builtin_amdgcn_mfma_f32_16x16x32_bf16(a[fm], b[fn], acc[fm][fn], 0, 0, 0);
        }
        __syncthreads();
    }

#pragma unroll
    for (int fm = 0; fm < 4; ++fm)
#pragma unroll
        for (int fn = 0; fn < 4; ++fn)
#pragma unroll
            for (int r = 0; r < 4; ++r) {
                int grow = m0 + wr * 64 + fm * 16 + ((lane >> 4) << 2) + r;
                int gcol = n0 + wc * 64 + fn * 16 + (lane & 15);
                Out[(size_t)grow * N + gcol] = acc[fm][fn][r];
            }
}

// ================= fused scores + softmax + PV =================
// Block = one (b,h), one 64-row Q strip. 4 waves, wave w owns rows w*16..w*16+15.
// Phase 1: per 128-col tile: S = qk^T*scale + prev (batched prefetch), write
//          scores, online m/l (intra-wave shfl over 16 col-lanes).
// Phase 2: re-read scores (batched, cache-hot), p=exp(s-m)/l, write attn (NT),
//          p->bf16->LDS, O += P@V. LDS phase-union = 32 KB.
__global__ __launch_bounds__(256, 4) void attn_fused(const unsigned short* __restrict__ qh,
                                                     const unsigned short* __restrict__ kh,
                                                     const unsigned short* __restrict__ vT,
                                                     const float* __restrict__ prev,
                                                     float* __restrict__ scores,
                                                     float* __restrict__ attn,
                                                     unsigned short* __restrict__ ctx) {
    const int z = blockIdx.z;         // b*NH + h
    const int m0 = blockIdx.x * 64;   // Q strip base
    const int tid = threadIdx.x;
    const int lane = tid & 63;
    const int w = tid >> 6;
    const int l15 = lane & 15, lhi = lane >> 4;

    __shared__ unsigned short smem[16384];     // 32 KB
    unsigned short* sQ = smem;                 // [64][64]  phase 1
    unsigned short* sK = smem + 4096;          // [128][64] phase 1
    unsigned short* sV = smem;                 // [64][128] phase 2
    unsigned short* sP = smem + 8192;          // [64][128] phase 2

    const unsigned short* Qz = qh + (size_t)z * S_LEN * DH;
    const unsigned short* Kz = kh + (size_t)z * S_LEN * DH;
    const unsigned short* Vz = vT + (size_t)z * DH * S_LEN;
    const size_t zbase = (size_t)z * S_LEN * S_LEN;
    const float scale = 0.125f;  // 1/sqrt(64)

    // stage Q strip (visible after first in-loop barrier pair)
#pragma unroll
    for (int i = 0; i < 2; ++i) {
        int c = i * 256 + tid;
        int row = c >> 3, col8 = c & 7;
        *reinterpret_cast<int4*>(sQ + row * 64 + ((col8 * 8) ^ ((row & 7) * 8))) =
            *reinterpret_cast<const int4*>(Qz + (size_t)(m0 + row) * DH + col8 * 8);
    }

    float m_r[4], l_r[4];
#pragma unroll
    for (int r = 0; r < 4; ++r) { m_r[r] = -1e30f; l_r[r] = 0.f; }

    const int rowb = w * 16 + lhi * 4;  // local row base of this lane's 4 rows

    // ---------- phase 1 ----------
    for (int kt = 0; kt < S_LEN / 128; ++kt) {
        const int n0 = kt * 128;
        // issue K-tile loads + prev loads (in flight across barrier+MFMA)
        int4 kreg[4];
#pragma unroll
        for (int i = 0; i < 4; ++i) {
            int c = i * 256 + tid;
            int row = c >> 3, col8 = c & 7;
            kreg[i] = *reinterpret_cast<const int4*>(Kz + (size_t)(n0 + row) * DH + col8 * 8);
        }
        float pv[32];
#pragma unroll
        for (int fn = 0; fn < 8; ++fn)
#pragma unroll
            for (int r = 0; r < 4; ++r)
                pv[fn * 4 + r] = __builtin_nontemporal_load(
                    prev + zbase + (size_t)(m0 + rowb + r) * S_LEN + n0 + fn * 16 + l15);

        __syncthreads();  // prior iter MFMA done reading sK
#pragma unroll
        for (int i = 0; i < 4; ++i) {
            int c = i * 256 + tid;
            int row = c >> 3, col8 = c & 7;
            *reinterpret_cast<int4*>(sK + row * 64 + ((col8 * 8) ^ ((row & 7) * 8))) = kreg[i];
        }
        __syncthreads();

        f32x4 acc[8];
#pragma unroll
        for (int fn = 0; fn < 8; ++fn) acc[fn] = (f32x4){0.f, 0.f, 0.f, 0.f};
#pragma unroll
        for (int kk = 0; kk < 2; ++kk) {
            bfrag a, b[8];
            int ra = w * 16 + l15;
            a = *reinterpret_cast<const bfrag*>(sQ + ra * 64 +
                                                ((kk * 32 + lhi * 8) ^ ((ra & 7) * 8)));
#pragma unroll
            for (int f = 0; f < 8; ++f) {
                int rb = f * 16 + l15;
                b[f] = *reinterpret_cast<const bfrag*>(sK + rb * 64 +
                                                       ((kk * 32 + lhi * 8) ^ ((rb & 7) * 8)));
            }
#pragma unroll
            for (int fn = 0; fn < 8; ++fn)
                acc[fn] = __builtin_amdgcn_mfma_f32_16x16x32_bf16(a, b[fn], acc[fn], 0, 0, 0);
        }

        // scale + prev, write scores, online m/l
#pragma unroll
        for (int fn = 0; fn < 8; ++fn)
#pragma unroll
            for (int r = 0; r < 4; ++r) {
                float s = acc[fn][r] * scale + pv[fn * 4 + r];
                scores[zbase + (size_t)(m0 + rowb + r) * S_LEN + n0 + fn * 16 + l15] = s;
                acc[fn][r] = s;
            }
#pragma unroll
        for (int r = 0; r < 4; ++r) {
            float pm = acc[0][r];
#pragma unroll
            for (int fn = 1; fn < 8; ++fn) pm = fmaxf(pm, acc[fn][r]);
            pm = fmaxf(pm, __shfl_xor(pm, 1));
            pm = fmaxf(pm, __shfl_xor(pm, 2));
            pm = fmaxf(pm, __shfl_xor(pm, 4));
            pm = fmaxf(pm, __shfl_xor(pm, 8));
            float mnew = fmaxf(m_r[r], pm);
            float psum = 0.f;
#pragma unroll
            for (int fn = 0; fn < 8; ++fn) psum += __expf(acc[fn][r] - mnew);
            psum += __shfl_xor(psum, 1);
            psum += __shfl_xor(psum, 2);
            psum += __shfl_xor(psum, 4);
            psum += __shfl_xor(psum, 8);
            l_r[r] = l_r[r] * __expf(m_r[r] - mnew) + psum;
            m_r[r] = mnew;
        }
    }

    float inv_l[4];
#pragma unroll
    for (int r = 0; r < 4; ++r) inv_l[r] = 1.0f / l_r[r];

    // ---------- phase 2 ----------
    f32x4 acco[4];
#pragma unroll
    for (int fn = 0; fn < 4; ++fn) acco[fn] = (f32x4){0.f, 0.f, 0.f, 0.f};

    for (int kt = 0; kt < S_LEN / 128; ++kt) {
        const int n0 = kt * 128;
        // issue V-tile loads + scores re-reads (in flight)
        int4 vreg[4];
#pragma unroll
        for (int i = 0; i < 4; ++i) {
            int c = i * 256 + tid;
            int row = c >> 4, col8 = c & 15;
            vreg[i] = *reinterpret_cast<const int4*>(Vz + (size_t)row * S_LEN + n0 + col8 * 8);
        }
        float sv[32];
#pragma unroll
        for (int fn = 0; fn < 8; ++fn)
#pragma unroll
            for (int r = 0; r < 4; ++r)
                sv[fn * 4 + r] =
                    scores[zbase + (size_t)(m0 + rowb + r) * S_LEN + n0 + fn * 16 + l15];

        __syncthreads();  // prior iter MFMA done reading sV/sP (and phase-1 tail for kt=0)
#pragma unroll
        for (int i = 0; i < 4; ++i) {
            int c = i * 256 + tid;
            int row = c >> 4, col8 = c & 15;
            *reinterpret_cast<int4*>(sV + row * 128 + ((col8 ^ (row & 7)) << 3)) = vreg[i];
        }
        // p = exp(s-m)/l, write attn (NT), stage p into sP
#pragma unroll
        for (int fn = 0; fn < 8; ++fn)
#pragma unroll
            for (int r = 0; r < 4; ++r) {
                float p = __expf(sv[fn * 4 + r] - m_r[r]) * inv_l[r];
                __builtin_nontemporal_store(
                    p, attn + zbase + (size_t)(m0 + rowb + r) * S_LEN + n0 + fn * 16 + l15);
                int prow = rowb + r, pcol = fn * 16 + l15;
                sP[prow * 128 + (((pcol >> 3) ^ (prow & 7)) << 3) + (pcol & 7)] = f2bf(p);
            }
        __syncthreads();
        // O += P @ V
#pragma unroll
        for (int kk = 0; kk < 4; ++kk) {
            bfrag a, b[4];
            int ra = w * 16 + l15;
            a = *reinterpret_cast<const bfrag*>(sP + ra * 128 +
                                                (((kk * 4 + lhi) ^ (ra & 7)) << 3));
#pragma unroll
            for (int f = 0; f < 4; ++f) {
                int rb = f * 16 + l15;
                b[f] = *reinterpret_cast<const bfrag*>(sV + rb * 128 +
                                                       (((kk * 4 + lhi) ^ (rb & 7)) << 3));
            }
#pragma unroll
            for (int fn = 0; fn < 4; ++fn)
                acco[fn] = __builtin_amdgcn_mfma_f32_16x16x32_bf16(a, b[fn], acco[fn], 0, 0, 0);
        }
    }

    // write ctx (b, s, h*DH + d) bf16
    const int b = z >> 4, h = z & 15;
#pragma unroll
    for (int fn = 0; fn < 4; ++fn)
#pragma unroll
        for (int r = 0; r < 4; ++r) {
            int s = m0 + rowb + r;
            int d = fn * 16 + l15;
            ctx[((size_t)(b * S_LEN + s)) * DM + h * DH + d] = f2bf(acco[fn][r]);
        }
}

extern "C" void kernel_launch(void* const* d_in, const int* in_sizes, int n_in, void* d_out,
                              int out_size, void* d_ws, size_t ws_size, hipStream_t stream) {
    const float* Q = (const float*)d_in[0];
    const float* K = (const float*)d_in[1];
    const float* V = (const float*)d_in[2];
    const float* prev = (const float*)d_in[3];
    const float* Wq = (const float*)d_in[4];
    const float* Wk = (const float*)d_in[5];
    const float* Wv = (const float*)d_in[6];
    const float* Wo = (const float*)d_in[7];

    float* out = (float*)d_out;
    float* attn = out + (size_t)BS * DM;
    float* scores = attn + (size_t)NB * NH * S_LEN * S_LEN;

    unsigned short* ws = (unsigned short*)d_ws;
    unsigned short* qh = ws;                      // (b,h,s,d) bf16
    unsigned short* kh = qh + (size_t)BS * DM;    // (b,h,s,d) bf16
    unsigned short* vT = kh + (size_t)BS * DM;    // (b,h,d,s) bf16
    unsigned short* ctx = vT + (size_t)BS * DM;   // (b,s,h*d) bf16

    // combined QKV projections (768 blocks, 3/CU)
    dim3 gq(DM / 128, BS / 128, 3);
    gemm_qkv<<<gq, 256, 0, stream>>>(Q, K, V, Wq, Wk, Wv, qh, kh, vT);

    // fused scores + softmax + PV (1024 blocks)
    dim3 ga(S_LEN / 64, 1, NB * NH);
    attn_fused<<<ga, 256, 0, stream>>>(qh, kh, vT, prev, scores, attn, ctx);

    // output projection
    dim3 gp(DM / 128, BS / 128, 1);
    gemm_out<<<gp, 256, 0, stream>>>(ctx, Wo, out);
}

// Round 4
// 755.486 us; speedup vs baseline: 1.6986x; 1.0910x over previous
//
#include <hip/hip_runtime.h>

#define S_LEN 2048
#define NH 16
#define DH 64
#define DM 1024
#define NB 2
#define BS 4096  // NB*S_LEN

typedef __attribute__((ext_vector_type(4))) float f32x4;
typedef __attribute__((ext_vector_type(8))) short bfrag;  // 8 bf16 in 4 VGPRs

__device__ __forceinline__ unsigned short f2bf(float f) {
    unsigned u = __builtin_bit_cast(unsigned, f);
    u += 0x7FFFu + ((u >> 16) & 1u);
    return (unsigned short)(u >> 16);
}

// barrier that waits only LDS ops (leaves global prefetch loads in flight)
__device__ __forceinline__ void bar_lgkm() {
    asm volatile("s_waitcnt lgkmcnt(0)" ::: "memory");
    __builtin_amdgcn_s_barrier();
}

// ================= combined QKV projection, 128x64 tile, LDS double-buffer =================
// z = 0/1/2 -> Q/K/V. C[m,n] = sum_k A[m,k]*W[n,k], A,W fp32 (cast in staging).
// z<2: write bf16 (b,h,s,d); z==2: write bf16 (b,h,d,s) for PV B-operand.
__global__ __launch_bounds__(256) void gemm_qkv(const float* __restrict__ Qi,
                                                const float* __restrict__ Ki,
                                                const float* __restrict__ Vi,
                                                const float* __restrict__ Wq,
                                                const float* __restrict__ Wk,
                                                const float* __restrict__ Wv,
                                                unsigned short* __restrict__ qh,
                                                unsigned short* __restrict__ kh,
                                                unsigned short* __restrict__ vT) {
    const int z = blockIdx.z;
    const float* A = (z == 0) ? Qi : (z == 1) ? Ki : Vi;
    const float* B = (z == 0) ? Wq : (z == 1) ? Wk : Wv;
    const int tid = threadIdx.x, lane = tid & 63;
    const int l15 = lane & 15, lhi = lane >> 4;
    const int w = tid >> 6, wr = w >> 1, wc = w & 1;
    const int m0 = blockIdx.y * 128, n0 = blockIdx.x * 64;
    const int K = DM;

    __shared__ unsigned short sA[2][128 * 64];
    __shared__ unsigned short sB[2][64 * 64];

    float4 va[8], vb[4];
    // prologue: load K-tile 0
#pragma unroll
    for (int i = 0; i < 8; ++i) {
        int c = i * 256 + tid, row = c >> 4, col4 = c & 15;
        va[i] = *reinterpret_cast<const float4*>(A + (size_t)(m0 + row) * K + col4 * 4);
    }
#pragma unroll
    for (int i = 0; i < 4; ++i) {
        int c = i * 256 + tid, row = c >> 4, col4 = c & 15;
        vb[i] = *reinterpret_cast<const float4*>(B + (size_t)(n0 + row) * K + col4 * 4);
    }

    f32x4 acc[4][2];
#pragma unroll
    for (int i = 0; i < 4; ++i)
#pragma unroll
        for (int j = 0; j < 2; ++j) acc[i][j] = (f32x4){0.f, 0.f, 0.f, 0.f};

    for (int t = 0; t < 16; ++t) {
        unsigned short* pA = sA[t & 1];
        unsigned short* pB = sB[t & 1];
        // convert + ds_write tile t (vmcnt waits inserted by compiler here)
#pragma unroll
        for (int i = 0; i < 8; ++i) {
            int c = i * 256 + tid, row = c >> 4, col4 = c & 15;
            ushort4 o;
            o.x = f2bf(va[i].x); o.y = f2bf(va[i].y); o.z = f2bf(va[i].z); o.w = f2bf(va[i].w);
            *reinterpret_cast<ushort4*>(pA + row * 64 + ((col4 * 4) ^ ((row & 7) * 8))) = o;
        }
#pragma unroll
        for (int i = 0; i < 4; ++i) {
            int c = i * 256 + tid, row = c >> 4, col4 = c & 15;
            ushort4 o;
            o.x = f2bf(vb[i].x); o.y = f2bf(vb[i].y); o.z = f2bf(vb[i].z); o.w = f2bf(vb[i].w);
            *reinterpret_cast<ushort4*>(pB + row * 64 + ((col4 * 4) ^ ((row & 7) * 8))) = o;
        }
        // issue loads for tile t+1 (fly through barrier + MFMA)
        if (t < 15) {
            const int k0 = (t + 1) * 64;
#pragma unroll
            for (int i = 0; i < 8; ++i) {
                int c = i * 256 + tid, row = c >> 4, col4 = c & 15;
                va[i] = *reinterpret_cast<const float4*>(A + (size_t)(m0 + row) * K + k0 + col4 * 4);
            }
#pragma unroll
            for (int i = 0; i < 4; ++i) {
                int c = i * 256 + tid, row = c >> 4, col4 = c & 15;
                vb[i] = *reinterpret_cast<const float4*>(B + (size_t)(n0 + row) * K + k0 + col4 * 4);
            }
        }
        bar_lgkm();  // tile t visible; single barrier per step (dbuf makes it safe)
#pragma unroll
        for (int kk = 0; kk < 2; ++kk) {
            bfrag a[4], b[2];
#pragma unroll
            for (int f = 0; f < 4; ++f) {
                int ra = wr * 64 + f * 16 + l15;
                a[f] = *reinterpret_cast<const bfrag*>(pA + ra * 64 +
                                                       ((kk * 32 + lhi * 8) ^ ((ra & 7) * 8)));
            }
#pragma unroll
            for (int f = 0; f < 2; ++f) {
                int rb = wc * 32 + f * 16 + l15;
                b[f] = *reinterpret_cast<const bfrag*>(pB + rb * 64 +
                                                       ((kk * 32 + lhi * 8) ^ ((rb & 7) * 8)));
            }
#pragma unroll
            for (int fm = 0; fm < 4; ++fm)
#pragma unroll
                for (int fn = 0; fn < 2; ++fn)
                    acc[fm][fn] =
                        __builtin_amdgcn_mfma_f32_16x16x32_bf16(a[fm], b[fn], acc[fm][fn], 0, 0, 0);
        }
    }

    if (z == 2) {
#pragma unroll
        for (int fm = 0; fm < 4; ++fm)
#pragma unroll
            for (int fn = 0; fn < 2; ++fn) {
                int sbase = m0 + wr * 64 + fm * 16 + (lhi << 2);
                int gcol = n0 + wc * 32 + fn * 16 + l15;
                int b = sbase >> 11, s = sbase & 2047, h = gcol >> 6, d = gcol & 63;
                ushort4 o;
                o.x = f2bf(acc[fm][fn][0]); o.y = f2bf(acc[fm][fn][1]);
                o.z = f2bf(acc[fm][fn][2]); o.w = f2bf(acc[fm][fn][3]);
                *reinterpret_cast<ushort4*>(vT + ((size_t)(b * NH + h) * DH + d) * S_LEN + s) = o;
            }
    } else {
        unsigned short* Out = (z == 0) ? qh : kh;
#pragma unroll
        for (int fm = 0; fm < 4; ++fm)
#pragma unroll
            for (int fn = 0; fn < 2; ++fn)
#pragma unroll
                for (int r = 0; r < 4; ++r) {
                    int grow = m0 + wr * 64 + fm * 16 + (lhi << 2) + r;
                    int gcol = n0 + wc * 32 + fn * 16 + l15;
                    int b = grow >> 11, s = grow & 2047, h = gcol >> 6, d = gcol & 63;
                    Out[((size_t)(b * NH + h) * S_LEN + s) * DH + d] = f2bf(acc[fm][fn][r]);
                }
    }
}

// ================= output projection: out[m,n] = sum_k ctx[m,k]*Wo[n,k] =================
// ctx bf16, Wo fp32, out fp32. 128x64 tile, LDS double-buffer, same pipeline.
__global__ __launch_bounds__(256) void gemm_out(const unsigned short* __restrict__ A,
                                                const float* __restrict__ B,
                                                float* __restrict__ Out) {
    const int tid = threadIdx.x, lane = tid & 63;
    const int l15 = lane & 15, lhi = lane >> 4;
    const int w = tid >> 6, wr = w >> 1, wc = w & 1;
    const int m0 = blockIdx.y * 128, n0 = blockIdx.x * 64;
    const int K = DM, N = DM;

    __shared__ unsigned short sA[2][128 * 64];
    __shared__ unsigned short sB[2][64 * 64];

    int4 va[4];
    float4 vb[4];
#pragma unroll
    for (int i = 0; i < 4; ++i) {
        int c = i * 256 + tid, row = c >> 3, col8 = c & 7;
        va[i] = *reinterpret_cast<const int4*>(A + (size_t)(m0 + row) * K + col8 * 8);
    }
#pragma unroll
    for (int i = 0; i < 4; ++i) {
        int c = i * 256 + tid, row = c >> 4, col4 = c & 15;
        vb[i] = *reinterpret_cast<const float4*>(B + (size_t)(n0 + row) * K + col4 * 4);
    }

    f32x4 acc[4][2];
#pragma unroll
    for (int i = 0; i < 4; ++i)
#pragma unroll
        for (int j = 0; j < 2; ++j) acc[i][j] = (f32x4){0.f, 0.f, 0.f, 0.f};

    for (int t = 0; t < 16; ++t) {
        unsigned short* pA = sA[t & 1];
        unsigned short* pB = sB[t & 1];
#pragma unroll
        for (int i = 0; i < 4; ++i) {
            int c = i * 256 + tid, row = c >> 3, col8 = c & 7;
            *reinterpret_cast<int4*>(pA + row * 64 + ((col8 * 8) ^ ((row & 7) * 8))) = va[i];
        }
#pragma unroll
        for (int i = 0; i < 4; ++i) {
            int c = i * 256 + tid, row = c >> 4, col4 = c & 15;
            ushort4 o;
            o.x = f2bf(vb[i].x); o.y = f2bf(vb[i].y); o.z = f2bf(vb[i].z); o.w = f2bf(vb[i].w);
            *reinterpret_cast<ushort4*>(pB + row * 64 + ((col4 * 4) ^ ((row & 7) * 8))) = o;
        }
        if (t < 15) {
            const int k0 = (t + 1) * 64;
#pragma unroll
            for (int i = 0; i < 4; ++i) {
                int c = i * 256 + tid, row = c >> 3, col8 = c & 7;
                va[i] = *reinterpret_cast<const int4*>(A + (size_t)(m0 + row) * K + k0 + col8 * 8);
            }
#pragma unroll
            for (int i = 0; i < 4; ++i) {
                int c = i * 256 + tid, row = c >> 4, col4 = c & 15;
                vb[i] = *reinterpret_cast<const float4*>(B + (size_t)(n0 + row) * K + k0 + col4 * 4);
            }
        }
        bar_lgkm();
#pragma unroll
        for (int kk = 0; kk < 2; ++kk) {
            bfrag a[4], b[2];
#pragma unroll
            for (int f = 0; f < 4; ++f) {
                int ra = wr * 64 + f * 16 + l15;
                a[f] = *reinterpret_cast<const bfrag*>(pA + ra * 64 +
                                                       ((kk * 32 + lhi * 8) ^ ((ra & 7) * 8)));
            }
#pragma unroll
            for (int f = 0; f < 2; ++f) {
                int rb = wc * 32 + f * 16 + l15;
                b[f] = *reinterpret_cast<const bfrag*>(pB + rb * 64 +
                                                       ((kk * 32 + lhi * 8) ^ ((rb & 7) * 8)));
            }
#pragma unroll
            for (int fm = 0; fm < 4; ++fm)
#pragma unroll
                for (int fn = 0; fn < 2; ++fn)
                    acc[fm][fn] =
                        __builtin_amdgcn_mfma_f32_16x16x32_bf16(a[fm], b[fn], acc[fm][fn], 0, 0, 0);
        }
    }

#pragma unroll
    for (int fm = 0; fm < 4; ++fm)
#pragma unroll
        for (int fn = 0; fn < 2; ++fn)
#pragma unroll
            for (int r = 0; r < 4; ++r) {
                int grow = m0 + wr * 64 + fm * 16 + (lhi << 2) + r;
                int gcol = n0 + wc * 32 + fn * 16 + l15;
                Out[(size_t)grow * N + gcol] = acc[fm][fn][r];
            }
}

// ================= fused scores + softmax + PV =================
// Block = one (b,h), one 64-row Q strip. 4 waves, wave w owns rows w*16..w*16+15.
// prev / K / V / scores streams software-pipelined one 128-col tile ahead.
__global__ __launch_bounds__(256, 4) void attn_fused(const unsigned short* __restrict__ qh,
                                                     const unsigned short* __restrict__ kh,
                                                     const unsigned short* __restrict__ vT,
                                                     const float* __restrict__ prev,
                                                     float* __restrict__ scores,
                                                     float* __restrict__ attn,
                                                     unsigned short* __restrict__ ctx) {
    const int z = blockIdx.z;         // b*NH + h
    const int m0 = blockIdx.x * 64;   // Q strip base
    const int tid = threadIdx.x;
    const int lane = tid & 63;
    const int w = tid >> 6;
    const int l15 = lane & 15, lhi = lane >> 4;

    __shared__ unsigned short smem[16384];     // 32 KB
    unsigned short* sQ = smem;                 // [64][64]  phase 1
    unsigned short* sK = smem + 4096;          // [128][64] phase 1
    unsigned short* sV = smem;                 // [64][128] phase 2
    unsigned short* sP = smem + 8192;          // [64][128] phase 2

    const unsigned short* Qz = qh + (size_t)z * S_LEN * DH;
    const unsigned short* Kz = kh + (size_t)z * S_LEN * DH;
    const unsigned short* Vz = vT + (size_t)z * DH * S_LEN;
    const size_t zbase = (size_t)z * S_LEN * S_LEN;
    const float scale = 0.125f;  // 1/sqrt(64)
    const int rowb = w * 16 + lhi * 4;

    // stage Q strip
#pragma unroll
    for (int i = 0; i < 2; ++i) {
        int c = i * 256 + tid, row = c >> 3, col8 = c & 7;
        *reinterpret_cast<int4*>(sQ + row * 64 + ((col8 * 8) ^ ((row & 7) * 8))) =
            *reinterpret_cast<const int4*>(Qz + (size_t)(m0 + row) * DH + col8 * 8);
    }

    float m_r[4], l_r[4];
#pragma unroll
    for (int r = 0; r < 4; ++r) { m_r[r] = -1e30f; l_r[r] = 0.f; }

    // prologue: tile-0 K + prev
    int4 kreg[4];
#pragma unroll
    for (int i = 0; i < 4; ++i) {
        int c = i * 256 + tid, row = c >> 3, col8 = c & 7;
        kreg[i] = *reinterpret_cast<const int4*>(Kz + (size_t)row * DH + col8 * 8);
    }
    float pv[32];
#pragma unroll
    for (int fn = 0; fn < 8; ++fn)
#pragma unroll
        for (int r = 0; r < 4; ++r)
            pv[fn * 4 + r] = __builtin_nontemporal_load(
                prev + zbase + (size_t)(m0 + rowb + r) * S_LEN + fn * 16 + l15);

    // ---------- phase 1 ----------
    for (int kt = 0; kt < S_LEN / 128; ++kt) {
        const int n0 = kt * 128;
        bar_lgkm();  // prior MFMA ds_reads of sK complete everywhere
#pragma unroll
        for (int i = 0; i < 4; ++i) {
            int c = i * 256 + tid, row = c >> 3, col8 = c & 7;
            *reinterpret_cast<int4*>(sK + row * 64 + ((col8 * 8) ^ ((row & 7) * 8))) = kreg[i];
        }
        if (kt < 15) {
            const int n1 = n0 + 128;
#pragma unroll
            for (int i = 0; i < 4; ++i) {
                int c = i * 256 + tid, row = c >> 3, col8 = c & 7;
                kreg[i] = *reinterpret_cast<const int4*>(Kz + (size_t)(n1 + row) * DH + col8 * 8);
            }
        }
        bar_lgkm();  // sK visible

        f32x4 acc[8];
#pragma unroll
        for (int fn = 0; fn < 8; ++fn) acc[fn] = (f32x4){0.f, 0.f, 0.f, 0.f};
#pragma unroll
        for (int kk = 0; kk < 2; ++kk) {
            int ra = w * 16 + l15;
            bfrag a = *reinterpret_cast<const bfrag*>(sQ + ra * 64 +
                                                      ((kk * 32 + lhi * 8) ^ ((ra & 7) * 8)));
            bfrag b[8];
#pragma unroll
            for (int f = 0; f < 8; ++f) {
                int rb = f * 16 + l15;
                b[f] = *reinterpret_cast<const bfrag*>(sK + rb * 64 +
                                                       ((kk * 32 + lhi * 8) ^ ((rb & 7) * 8)));
            }
#pragma unroll
            for (int fn = 0; fn < 8; ++fn)
                acc[fn] = __builtin_amdgcn_mfma_f32_16x16x32_bf16(a, b[fn], acc[fn], 0, 0, 0);
        }

        // consume prev, then immediately refill prev(t+1)
#pragma unroll
        for (int fn = 0; fn < 8; ++fn)
#pragma unroll
            for (int r = 0; r < 4; ++r) acc[fn][r] = acc[fn][r] * scale + pv[fn * 4 + r];
        if (kt < 15) {
            const int n1 = n0 + 128;
#pragma unroll
            for (int fn = 0; fn < 8; ++fn)
#pragma unroll
                for (int r = 0; r < 4; ++r)
                    pv[fn * 4 + r] = __builtin_nontemporal_load(
                        prev + zbase + (size_t)(m0 + rowb + r) * S_LEN + n1 + fn * 16 + l15);
        }
        // write scores
#pragma unroll
        for (int fn = 0; fn < 8; ++fn)
#pragma unroll
            for (int r = 0; r < 4; ++r)
                scores[zbase + (size_t)(m0 + rowb + r) * S_LEN + n0 + fn * 16 + l15] = acc[fn][r];
        // online softmax state
#pragma unroll
        for (int r = 0; r < 4; ++r) {
            float pm = acc[0][r];
#pragma unroll
            for (int fn = 1; fn < 8; ++fn) pm = fmaxf(pm, acc[fn][r]);
            pm = fmaxf(pm, __shfl_xor(pm, 1));
            pm = fmaxf(pm, __shfl_xor(pm, 2));
            pm = fmaxf(pm, __shfl_xor(pm, 4));
            pm = fmaxf(pm, __shfl_xor(pm, 8));
            float mnew = fmaxf(m_r[r], pm);
            float psum = 0.f;
#pragma unroll
            for (int fn = 0; fn < 8; ++fn) psum += __expf(acc[fn][r] - mnew);
            psum += __shfl_xor(psum, 1);
            psum += __shfl_xor(psum, 2);
            psum += __shfl_xor(psum, 4);
            psum += __shfl_xor(psum, 8);
            l_r[r] = l_r[r] * __expf(m_r[r] - mnew) + psum;
            m_r[r] = mnew;
        }
    }

    float inv_l[4];
#pragma unroll
    for (int r = 0; r < 4; ++r) inv_l[r] = 1.0f / l_r[r];

    // ---------- phase 2 ----------
    f32x4 acco[4];
#pragma unroll
    for (int fn = 0; fn < 4; ++fn) acco[fn] = (f32x4){0.f, 0.f, 0.f, 0.f};

    int4 vreg[4];
#pragma unroll
    for (int i = 0; i < 4; ++i) {
        int c = i * 256 + tid, row = c >> 4, col8 = c & 15;
        vreg[i] = *reinterpret_cast<const int4*>(Vz + (size_t)row * S_LEN + col8 * 8);
    }
    float sv[32];
#pragma unroll
    for (int fn = 0; fn < 8; ++fn)
#pragma unroll
        for (int r = 0; r < 4; ++r)
            sv[fn * 4 + r] = scores[zbase + (size_t)(m0 + rowb + r) * S_LEN + fn * 16 + l15];

    for (int kt = 0; kt < S_LEN / 128; ++kt) {
        const int n0 = kt * 128;
        bar_lgkm();  // prior MFMA ds_reads of sV/sP complete (covers phase-1 tail at kt=0)
#pragma unroll
        for (int i = 0; i < 4; ++i) {
            int c = i * 256 + tid, row = c >> 4, col8 = c & 15;
            *reinterpret_cast<int4*>(sV + row * 128 + ((col8 ^ (row & 7)) << 3)) = vreg[i];
        }
        if (kt < 15) {
            const int n1 = n0 + 128;
#pragma unroll
            for (int i = 0; i < 4; ++i) {
                int c = i * 256 + tid, row = c >> 4, col8 = c & 15;
                vreg[i] = *reinterpret_cast<const int4*>(Vz + (size_t)row * S_LEN + n1 + col8 * 8);
            }
        }
        // p = exp(s-m)/l, write attn (NT), stage p into sP
#pragma unroll
        for (int fn = 0; fn < 8; ++fn)
#pragma unroll
            for (int r = 0; r < 4; ++r) {
                float p = __expf(sv[fn * 4 + r] - m_r[r]) * inv_l[r];
                __builtin_nontemporal_store(
                    p, attn + zbase + (size_t)(m0 + rowb + r) * S_LEN + n0 + fn * 16 + l15);
                int prow = rowb + r, pcol = fn * 16 + l15;
                sP[prow * 128 + (((pcol >> 3) ^ (prow & 7)) << 3) + (pcol & 7)] = f2bf(p);
            }
        if (kt < 15) {
            const int n1 = n0 + 128;
#pragma unroll
            for (int fn = 0; fn < 8; ++fn)
#pragma unroll
                for (int r = 0; r < 4; ++r)
                    sv[fn * 4 + r] =
                        scores[zbase + (size_t)(m0 + rowb + r) * S_LEN + n1 + fn * 16 + l15];
        }
        bar_lgkm();  // sV/sP visible
        // O += P @ V
#pragma unroll
        for (int kk = 0; kk < 4; ++kk) {
            int ra = w * 16 + l15;
            bfrag a = *reinterpret_cast<const bfrag*>(sP + ra * 128 +
                                                      (((kk * 4 + lhi) ^ (ra & 7)) << 3));
            bfrag b[4];
#pragma unroll
            for (int f = 0; f < 4; ++f) {
                int rb = f * 16 + l15;
                b[f] = *reinterpret_cast<const bfrag*>(sV + rb * 128 +
                                                       (((kk * 4 + lhi) ^ (rb & 7)) << 3));
            }
#pragma unroll
            for (int fn = 0; fn < 4; ++fn)
                acco[fn] = __builtin_amdgcn_mfma_f32_16x16x32_bf16(a, b[fn], acco[fn], 0, 0, 0);
        }
    }

    // write ctx (b, s, h*DH + d) bf16
    const int b = z >> 4, h = z & 15;
#pragma unroll
    for (int fn = 0; fn < 4; ++fn)
#pragma unroll
        for (int r = 0; r < 4; ++r) {
            int s = m0 + rowb + r;
            int d = fn * 16 + l15;
            ctx[((size_t)(b * S_LEN + s)) * DM + h * DH + d] = f2bf(acco[fn][r]);
        }
}

extern "C" void kernel_launch(void* const* d_in, const int* in_sizes, int n_in, void* d_out,
                              int out_size, void* d_ws, size_t ws_size, hipStream_t stream) {
    const float* Q = (const float*)d_in[0];
    const float* K = (const float*)d_in[1];
    const float* V = (const float*)d_in[2];
    const float* prev = (const float*)d_in[3];
    const float* Wq = (const float*)d_in[4];
    const float* Wk = (const float*)d_in[5];
    const float* Wv = (const float*)d_in[6];
    const float* Wo = (const float*)d_in[7];

    float* out = (float*)d_out;
    float* attn = out + (size_t)BS * DM;
    float* scores = attn + (size_t)NB * NH * S_LEN * S_LEN;

    unsigned short* ws = (unsigned short*)d_ws;
    unsigned short* qh = ws;                      // (b,h,s,d) bf16
    unsigned short* kh = qh + (size_t)BS * DM;    // (b,h,s,d) bf16
    unsigned short* vT = kh + (size_t)BS * DM;    // (b,h,d,s) bf16
    unsigned short* ctx = vT + (size_t)BS * DM;   // (b,s,h*d) bf16

    // combined QKV projections (1536 blocks, 3/CU LDS-resident)
    dim3 gq(DM / 64, BS / 128, 3);
    gemm_qkv<<<gq, 256, 0, stream>>>(Q, K, V, Wq, Wk, Wv, qh, kh, vT);

    // fused scores + softmax + PV (1024 blocks)
    dim3 ga(S_LEN / 64, 1, NB * NH);
    attn_fused<<<ga, 256, 0, stream>>>(qh, kh, vT, prev, scores, attn, ctx);

    // output projection (512 blocks)
    dim3 gp(DM / 64, BS / 128, 1);
    gemm_out<<<gp, 256, 0, stream>>>(ctx, Wo, out);
}

// Round 5
// 727.892 us; speedup vs baseline: 1.7630x; 1.0379x over previous
//
#include <hip/hip_runtime.h>

#define S_LEN 2048
#define NH 16
#define DH 64
#define DM 1024
#define NB 2
#define BS 4096  // NB*S_LEN

typedef __attribute__((ext_vector_type(4))) float f32x4;
typedef __attribute__((ext_vector_type(8))) short bfrag;  // 8 bf16 in 4 VGPRs

__device__ __forceinline__ unsigned short f2bf(float f) {
    unsigned u = __builtin_bit_cast(unsigned, f);
    u += 0x7FFFu + ((u >> 16) & 1u);
    return (unsigned short)(u >> 16);
}

// barrier that waits only LDS ops (leaves global prefetch loads in flight)
__device__ __forceinline__ void bar_lgkm() {
    asm volatile("s_waitcnt lgkmcnt(0)" ::: "memory");
    __builtin_amdgcn_s_barrier();
}

// async global->LDS, 16B per lane; LDS dest must be wave-uniform base (+lane*16 implicit)
__device__ __forceinline__ void gld16(const unsigned short* g, unsigned short* l) {
    __builtin_amdgcn_global_load_lds((const __attribute__((address_space(1))) void*)g,
                                     (__attribute__((address_space(3))) void*)l, 16, 0, 0);
}

// ---------------- fp32 -> bf16 cast ----------------
__global__ __launch_bounds__(256) void cast_kernel(const float* __restrict__ in,
                                                   unsigned short* __restrict__ out, int n4) {
    int i = blockIdx.x * 256 + threadIdx.x;
    if (i < n4) {
        float4 v = reinterpret_cast<const float4*>(in)[i];
        ushort4 o;
        o.x = f2bf(v.x); o.y = f2bf(v.y); o.z = f2bf(v.z); o.w = f2bf(v.w);
        reinterpret_cast<ushort4*>(out)[i] = o;
    }
}

// ================= combined QKV projection (m97 structure) =================
// 128x128 tile, BK=64, global_load_lds staging with pre-swizzled source.
// z = 0/1/2 -> Q/K/V. C[m,n] = sum_k A[m,k]*W[n,k], all bf16.
// z<2: write bf16 (b,h,s,d); z==2: write bf16 (b,h,d,s) for PV B-operand.
__global__ __launch_bounds__(256) void gemm_qkv(const unsigned short* __restrict__ Qc,
                                                const unsigned short* __restrict__ Kc,
                                                const unsigned short* __restrict__ Vc,
                                                const unsigned short* __restrict__ Wqc,
                                                const unsigned short* __restrict__ Wkc,
                                                const unsigned short* __restrict__ Wvc,
                                                unsigned short* __restrict__ qh,
                                                unsigned short* __restrict__ kh,
                                                unsigned short* __restrict__ vT) {
    const int z = blockIdx.z;
    const unsigned short* A = (z == 0) ? Qc : (z == 1) ? Kc : Vc;
    const unsigned short* B = (z == 0) ? Wqc : (z == 1) ? Wkc : Wvc;
    const int tid = threadIdx.x, lane = tid & 63;
    const int l15 = lane & 15, lhi = lane >> 4;
    const int w = tid >> 6, wr = w >> 1, wc = w & 1;
    const int m0 = blockIdx.y * 128, n0 = blockIdx.x * 128;
    const int K = DM;
    const int lr8 = lane >> 3;             // row-in-8-row-group
    const int csw = (lane & 7) ^ lr8;      // swizzled 16B-chunk index (8 chunks/row)

    __shared__ unsigned short sA[128 * 64];
    __shared__ unsigned short sB[128 * 64];

    f32x4 acc[4][4];
#pragma unroll
    for (int i = 0; i < 4; ++i)
#pragma unroll
        for (int j = 0; j < 4; ++j) acc[i][j] = (f32x4){0.f, 0.f, 0.f, 0.f};

    for (int t = 0; t < 16; ++t) {
        const int k0 = t * 64;
        // stage: 16 x 1KB insts each for A and B (4 per wave each); LDS linear,
        // global source pre-swizzled so ds_read with same XOR is conflict-light
#pragma unroll
        for (int i = 0; i < 4; ++i) {
            int g = w * 4 + i;
            int row = g * 8 + lr8;
            gld16(A + (size_t)(m0 + row) * K + k0 + csw * 8, sA + g * 512);
            gld16(B + (size_t)(n0 + row) * K + k0 + csw * 8, sB + g * 512);
        }
        __syncthreads();  // drains vmcnt -> tiles visible
#pragma unroll
        for (int kk = 0; kk < 2; ++kk) {
            bfrag a[4], b[4];
#pragma unroll
            for (int f = 0; f < 4; ++f) {
                int ra = wr * 64 + f * 16 + l15;
                a[f] = *reinterpret_cast<const bfrag*>(
                    sA + ra * 64 + (((kk * 4 + lhi) ^ (ra & 7)) << 3));
                int rb = wc * 64 + f * 16 + l15;
                b[f] = *reinterpret_cast<const bfrag*>(
                    sB + rb * 64 + (((kk * 4 + lhi) ^ (rb & 7)) << 3));
            }
#pragma unroll
            for (int fm = 0; fm < 4; ++fm)
#pragma unroll
                for (int fn = 0; fn < 4; ++fn)
                    acc[fm][fn] =
                        __builtin_amdgcn_mfma_f32_16x16x32_bf16(a[fm], b[fn], acc[fm][fn], 0, 0, 0);
        }
        __syncthreads();  // done reading before next overwrite
    }

    if (z == 2) {
#pragma unroll
        for (int fm = 0; fm < 4; ++fm)
#pragma unroll
            for (int fn = 0; fn < 4; ++fn) {
                int sbase = m0 + wr * 64 + fm * 16 + (lhi << 2);
                int gcol = n0 + wc * 64 + fn * 16 + l15;
                int b = sbase >> 11, s = sbase & 2047, h = gcol >> 6, d = gcol & 63;
                ushort4 o;
                o.x = f2bf(acc[fm][fn][0]); o.y = f2bf(acc[fm][fn][1]);
                o.z = f2bf(acc[fm][fn][2]); o.w = f2bf(acc[fm][fn][3]);
                *reinterpret_cast<ushort4*>(vT + ((size_t)(b * NH + h) * DH + d) * S_LEN + s) = o;
            }
    } else {
        unsigned short* Out = (z == 0) ? qh : kh;
#pragma unroll
        for (int fm = 0; fm < 4; ++fm)
#pragma unroll
            for (int fn = 0; fn < 4; ++fn)
#pragma unroll
                for (int r = 0; r < 4; ++r) {
                    int grow = m0 + wr * 64 + fm * 16 + (lhi << 2) + r;
                    int gcol = n0 + wc * 64 + fn * 16 + l15;
                    int b = grow >> 11, s = grow & 2047, h = gcol >> 6, d = gcol & 63;
                    Out[((size_t)(b * NH + h) * S_LEN + s) * DH + d] = f2bf(acc[fm][fn][r]);
                }
    }
}

// ================= output projection: out[m,n] = sum_k ctx[m,k]*Wo[n,k] =================
// ctx bf16, Wo bf16 (pre-cast), out fp32. Same m97 structure.
__global__ __launch_bounds__(256) void gemm_out(const unsigned short* __restrict__ A,
                                                const unsigned short* __restrict__ B,
                                                float* __restrict__ Out) {
    const int tid = threadIdx.x, lane = tid & 63;
    const int l15 = lane & 15, lhi = lane >> 4;
    const int w = tid >> 6, wr = w >> 1, wc = w & 1;
    const int m0 = blockIdx.y * 128, n0 = blockIdx.x * 128;
    const int K = DM, N = DM;
    const int lr8 = lane >> 3;
    const int csw = (lane & 7) ^ lr8;

    __shared__ unsigned short sA[128 * 64];
    __shared__ unsigned short sB[128 * 64];

    f32x4 acc[4][4];
#pragma unroll
    for (int i = 0; i < 4; ++i)
#pragma unroll
        for (int j = 0; j < 4; ++j) acc[i][j] = (f32x4){0.f, 0.f, 0.f, 0.f};

    for (int t = 0; t < 16; ++t) {
        const int k0 = t * 64;
#pragma unroll
        for (int i = 0; i < 4; ++i) {
            int g = w * 4 + i;
            int row = g * 8 + lr8;
            gld16(A + (size_t)(m0 + row) * K + k0 + csw * 8, sA + g * 512);
            gld16(B + (size_t)(n0 + row) * K + k0 + csw * 8, sB + g * 512);
        }
        __syncthreads();
#pragma unroll
        for (int kk = 0; kk < 2; ++kk) {
            bfrag a[4], b[4];
#pragma unroll
            for (int f = 0; f < 4; ++f) {
                int ra = wr * 64 + f * 16 + l15;
                a[f] = *reinterpret_cast<const bfrag*>(
                    sA + ra * 64 + (((kk * 4 + lhi) ^ (ra & 7)) << 3));
                int rb = wc * 64 + f * 16 + l15;
                b[f] = *reinterpret_cast<const bfrag*>(
                    sB + rb * 64 + (((kk * 4 + lhi) ^ (rb & 7)) << 3));
            }
#pragma unroll
            for (int fm = 0; fm < 4; ++fm)
#pragma unroll
                for (int fn = 0; fn < 4; ++fn)
                    acc[fm][fn] =
                        __builtin_amdgcn_mfma_f32_16x16x32_bf16(a[fm], b[fn], acc[fm][fn], 0, 0, 0);
        }
        __syncthreads();
    }

#pragma unroll
    for (int fm = 0; fm < 4; ++fm)
#pragma unroll
        for (int fn = 0; fn < 4; ++fn)
#pragma unroll
            for (int r = 0; r < 4; ++r) {
                int grow = m0 + wr * 64 + fm * 16 + (lhi << 2) + r;
                int gcol = n0 + wc * 64 + fn * 16 + l15;
                Out[(size_t)grow * N + gcol] = acc[fm][fn][r];
            }
}

// ================= fused scores + softmax + PV (unchanged from round 4) =================
__global__ __launch_bounds__(256, 4) void attn_fused(const unsigned short* __restrict__ qh,
                                                     const unsigned short* __restrict__ kh,
                                                     const unsigned short* __restrict__ vT,
                                                     const float* __restrict__ prev,
                                                     float* __restrict__ scores,
                                                     float* __restrict__ attn,
                                                     unsigned short* __restrict__ ctx) {
    const int z = blockIdx.z;         // b*NH + h
    const int m0 = blockIdx.x * 64;   // Q strip base
    const int tid = threadIdx.x;
    const int lane = tid & 63;
    const int w = tid >> 6;
    const int l15 = lane & 15, lhi = lane >> 4;

    __shared__ unsigned short smem[16384];     // 32 KB
    unsigned short* sQ = smem;                 // [64][64]  phase 1
    unsigned short* sK = smem + 4096;          // [128][64] phase 1
    unsigned short* sV = smem;                 // [64][128] phase 2
    unsigned short* sP = smem + 8192;          // [64][128] phase 2

    const unsigned short* Qz = qh + (size_t)z * S_LEN * DH;
    const unsigned short* Kz = kh + (size_t)z * S_LEN * DH;
    const unsigned short* Vz = vT + (size_t)z * DH * S_LEN;
    const size_t zbase = (size_t)z * S_LEN * S_LEN;
    const float scale = 0.125f;  // 1/sqrt(64)
    const int rowb = w * 16 + lhi * 4;

    // stage Q strip
#pragma unroll
    for (int i = 0; i < 2; ++i) {
        int c = i * 256 + tid, row = c >> 3, col8 = c & 7;
        *reinterpret_cast<int4*>(sQ + row * 64 + ((col8 * 8) ^ ((row & 7) * 8))) =
            *reinterpret_cast<const int4*>(Qz + (size_t)(m0 + row) * DH + col8 * 8);
    }

    float m_r[4], l_r[4];
#pragma unroll
    for (int r = 0; r < 4; ++r) { m_r[r] = -1e30f; l_r[r] = 0.f; }

    // prologue: tile-0 K + prev
    int4 kreg[4];
#pragma unroll
    for (int i = 0; i < 4; ++i) {
        int c = i * 256 + tid, row = c >> 3, col8 = c & 7;
        kreg[i] = *reinterpret_cast<const int4*>(Kz + (size_t)row * DH + col8 * 8);
    }
    float pv[32];
#pragma unroll
    for (int fn = 0; fn < 8; ++fn)
#pragma unroll
        for (int r = 0; r < 4; ++r)
            pv[fn * 4 + r] = __builtin_nontemporal_load(
                prev + zbase + (size_t)(m0 + rowb + r) * S_LEN + fn * 16 + l15);

    // ---------- phase 1 ----------
    for (int kt = 0; kt < S_LEN / 128; ++kt) {
        const int n0 = kt * 128;
        bar_lgkm();  // prior MFMA ds_reads of sK complete everywhere
#pragma unroll
        for (int i = 0; i < 4; ++i) {
            int c = i * 256 + tid, row = c >> 3, col8 = c & 7;
            *reinterpret_cast<int4*>(sK + row * 64 + ((col8 * 8) ^ ((row & 7) * 8))) = kreg[i];
        }
        if (kt < 15) {
            const int n1 = n0 + 128;
#pragma unroll
            for (int i = 0; i < 4; ++i) {
                int c = i * 256 + tid, row = c >> 3, col8 = c & 7;
                kreg[i] = *reinterpret_cast<const int4*>(Kz + (size_t)(n1 + row) * DH + col8 * 8);
            }
        }
        bar_lgkm();  // sK visible

        f32x4 acc[8];
#pragma unroll
        for (int fn = 0; fn < 8; ++fn) acc[fn] = (f32x4){0.f, 0.f, 0.f, 0.f};
#pragma unroll
        for (int kk = 0; kk < 2; ++kk) {
            int ra = w * 16 + l15;
            bfrag a = *reinterpret_cast<const bfrag*>(sQ + ra * 64 +
                                                      ((kk * 32 + lhi * 8) ^ ((ra & 7) * 8)));
            bfrag b[8];
#pragma unroll
            for (int f = 0; f < 8; ++f) {
                int rb = f * 16 + l15;
                b[f] = *reinterpret_cast<const bfrag*>(sK + rb * 64 +
                                                       ((kk * 32 + lhi * 8) ^ ((rb & 7) * 8)));
            }
#pragma unroll
            for (int fn = 0; fn < 8; ++fn)
                acc[fn] = __builtin_amdgcn_mfma_f32_16x16x32_bf16(a, b[fn], acc[fn], 0, 0, 0);
        }

        // consume prev, then immediately refill prev(t+1)
#pragma unroll
        for (int fn = 0; fn < 8; ++fn)
#pragma unroll
            for (int r = 0; r < 4; ++r) acc[fn][r] = acc[fn][r] * scale + pv[fn * 4 + r];
        if (kt < 15) {
            const int n1 = n0 + 128;
#pragma unroll
            for (int fn = 0; fn < 8; ++fn)
#pragma unroll
                for (int r = 0; r < 4; ++r)
                    pv[fn * 4 + r] = __builtin_nontemporal_load(
                        prev + zbase + (size_t)(m0 + rowb + r) * S_LEN + n1 + fn * 16 + l15);
        }
        // write scores
#pragma unroll
        for (int fn = 0; fn < 8; ++fn)
#pragma unroll
            for (int r = 0; r < 4; ++r)
                scores[zbase + (size_t)(m0 + rowb + r) * S_LEN + n0 + fn * 16 + l15] = acc[fn][r];
        // online softmax state
#pragma unroll
        for (int r = 0; r < 4; ++r) {
            float pm = acc[0][r];
#pragma unroll
            for (int fn = 1; fn < 8; ++fn) pm = fmaxf(pm, acc[fn][r]);
            pm = fmaxf(pm, __shfl_xor(pm, 1));
            pm = fmaxf(pm, __shfl_xor(pm, 2));
            pm = fmaxf(pm, __shfl_xor(pm, 4));
            pm = fmaxf(pm, __shfl_xor(pm, 8));
            float mnew = fmaxf(m_r[r], pm);
            float psum = 0.f;
#pragma unroll
            for (int fn = 0; fn < 8; ++fn) psum += __expf(acc[fn][r] - mnew);
            psum += __shfl_xor(psum, 1);
            psum += __shfl_xor(psum, 2);
            psum += __shfl_xor(psum, 4);
            psum += __shfl_xor(psum, 8);
            l_r[r] = l_r[r] * __expf(m_r[r] - mnew) + psum;
            m_r[r] = mnew;
        }
    }

    float inv_l[4];
#pragma unroll
    for (int r = 0; r < 4; ++r) inv_l[r] = 1.0f / l_r[r];

    // ---------- phase 2 ----------
    f32x4 acco[4];
#pragma unroll
    for (int fn = 0; fn < 4; ++fn) acco[fn] = (f32x4){0.f, 0.f, 0.f, 0.f};

    int4 vreg[4];
#pragma unroll
    for (int i = 0; i < 4; ++i) {
        int c = i * 256 + tid, row = c >> 4, col8 = c & 15;
        vreg[i] = *reinterpret_cast<const int4*>(Vz + (size_t)row * S_LEN + col8 * 8);
    }
    float sv[32];
#pragma unroll
    for (int fn = 0; fn < 8; ++fn)
#pragma unroll
        for (int r = 0; r < 4; ++r)
            sv[fn * 4 + r] = scores[zbase + (size_t)(m0 + rowb + r) * S_LEN + fn * 16 + l15];

    for (int kt = 0; kt < S_LEN / 128; ++kt) {
        const int n0 = kt * 128;
        bar_lgkm();  // prior MFMA ds_reads of sV/sP complete (covers phase-1 tail at kt=0)
#pragma unroll
        for (int i = 0; i < 4; ++i) {
            int c = i * 256 + tid, row = c >> 4, col8 = c & 15;
            *reinterpret_cast<int4*>(sV + row * 128 + ((col8 ^ (row & 7)) << 3)) = vreg[i];
        }
        if (kt < 15) {
            const int n1 = n0 + 128;
#pragma unroll
            for (int i = 0; i < 4; ++i) {
                int c = i * 256 + tid, row = c >> 4, col8 = c & 15;
                vreg[i] = *reinterpret_cast<const int4*>(Vz + (size_t)row * S_LEN + n1 + col8 * 8);
            }
        }
        // p = exp(s-m)/l, write attn (NT), stage p into sP
#pragma unroll
        for (int fn = 0; fn < 8; ++fn)
#pragma unroll
            for (int r = 0; r < 4; ++r) {
                float p = __expf(sv[fn * 4 + r] - m_r[r]) * inv_l[r];
                __builtin_nontemporal_store(
                    p, attn + zbase + (size_t)(m0 + rowb + r) * S_LEN + n0 + fn * 16 + l15);
                int prow = rowb + r, pcol = fn * 16 + l15;
                sP[prow * 128 + (((pcol >> 3) ^ (prow & 7)) << 3) + (pcol & 7)] = f2bf(p);
            }
        if (kt < 15) {
            const int n1 = n0 + 128;
#pragma unroll
            for (int fn = 0; fn < 8; ++fn)
#pragma unroll
                for (int r = 0; r < 4; ++r)
                    sv[fn * 4 + r] =
                        scores[zbase + (size_t)(m0 + rowb + r) * S_LEN + n1 + fn * 16 + l15];
        }
        bar_lgkm();  // sV/sP visible
        // O += P @ V
#pragma unroll
        for (int kk = 0; kk < 4; ++kk) {
            int ra = w * 16 + l15;
            bfrag a = *reinterpret_cast<const bfrag*>(sP + ra * 128 +
                                                      (((kk * 4 + lhi) ^ (ra & 7)) << 3));
            bfrag b[4];
#pragma unroll
            for (int f = 0; f < 4; ++f) {
                int rb = f * 16 + l15;
                b[f] = *reinterpret_cast<const bfrag*>(sV + rb * 128 +
                                                       (((kk * 4 + lhi) ^ (rb & 7)) << 3));
            }
#pragma unroll
            for (int fn = 0; fn < 4; ++fn)
                acco[fn] = __builtin_amdgcn_mfma_f32_16x16x32_bf16(a, b[fn], acco[fn], 0, 0, 0);
        }
    }

    // write ctx (b, s, h*DH + d) bf16
    const int b = z >> 4, h = z & 15;
#pragma unroll
    for (int fn = 0; fn < 4; ++fn)
#pragma unroll
        for (int r = 0; r < 4; ++r) {
            int s = m0 + rowb + r;
            int d = fn * 16 + l15;
            ctx[((size_t)(b * S_LEN + s)) * DM + h * DH + d] = f2bf(acco[fn][r]);
        }
}

extern "C" void kernel_launch(void* const* d_in, const int* in_sizes, int n_in, void* d_out,
                              int out_size, void* d_ws, size_t ws_size, hipStream_t stream) {
    const float* Q = (const float*)d_in[0];
    const float* K = (const float*)d_in[1];
    const float* V = (const float*)d_in[2];
    const float* prev = (const float*)d_in[3];
    const float* Wq = (const float*)d_in[4];
    const float* Wk = (const float*)d_in[5];
    const float* Wv = (const float*)d_in[6];
    const float* Wo = (const float*)d_in[7];

    float* out = (float*)d_out;
    float* attn = out + (size_t)BS * DM;
    float* scores = attn + (size_t)NB * NH * S_LEN * S_LEN;

    unsigned short* ws = (unsigned short*)d_ws;
    unsigned short* Qc = ws;                       // bf16 [4096][1024]
    unsigned short* Kc = Qc + (size_t)BS * DM;
    unsigned short* Vc = Kc + (size_t)BS * DM;
    unsigned short* Wqc = Vc + (size_t)BS * DM;    // bf16 [1024][1024]
    unsigned short* Wkc = Wqc + (size_t)DM * DM;
    unsigned short* Wvc = Wkc + (size_t)DM * DM;
    unsigned short* Woc = Wvc + (size_t)DM * DM;
    unsigned short* qh = Woc + (size_t)DM * DM;    // (b,h,s,d) bf16
    unsigned short* kh = qh + (size_t)BS * DM;     // (b,h,s,d) bf16
    unsigned short* vT = kh + (size_t)BS * DM;     // (b,h,d,s) bf16
    unsigned short* ctx = vT + (size_t)BS * DM;    // (b,s,h*d) bf16

    // casts
    cast_kernel<<<BS * DM / 4 / 256, 256, 0, stream>>>(Q, Qc, BS * DM / 4);
    cast_kernel<<<BS * DM / 4 / 256, 256, 0, stream>>>(K, Kc, BS * DM / 4);
    cast_kernel<<<BS * DM / 4 / 256, 256, 0, stream>>>(V, Vc, BS * DM / 4);
    cast_kernel<<<DM * DM / 4 / 256, 256, 0, stream>>>(Wq, Wqc, DM * DM / 4);
    cast_kernel<<<DM * DM / 4 / 256, 256, 0, stream>>>(Wk, Wkc, DM * DM / 4);
    cast_kernel<<<DM * DM / 4 / 256, 256, 0, stream>>>(Wv, Wvc, DM * DM / 4);
    cast_kernel<<<DM * DM / 4 / 256, 256, 0, stream>>>(Wo, Woc, DM * DM / 4);

    // combined QKV projections (768 blocks, m97-structure)
    dim3 gq(DM / 128, BS / 128, 3);
    gemm_qkv<<<gq, 256, 0, stream>>>(Qc, Kc, Vc, Wqc, Wkc, Wvc, qh, kh, vT);

    // fused scores + softmax + PV (1024 blocks)
    dim3 ga(S_LEN / 64, 1, NB * NH);
    attn_fused<<<ga, 256, 0, stream>>>(qh, kh, vT, prev, scores, attn, ctx);

    // output projection (256 blocks)
    dim3 gp(DM / 128, BS / 128, 1);
    gemm_out<<<gp, 256, 0, stream>>>(ctx, Woc, out);
}

// Round 6
// 671.071 us; speedup vs baseline: 1.9123x; 1.0847x over previous
//
#include <hip/hip_runtime.h>

#define S_LEN 2048
#define NH 16
#define DH 64
#define DM 1024
#define NB 2
#define BS 4096  // NB*S_LEN

typedef __attribute__((ext_vector_type(4))) float f32x4;
typedef __attribute__((ext_vector_type(8))) short bfrag;  // 8 bf16 in 4 VGPRs

__device__ __forceinline__ unsigned short f2bf(float f) {
    unsigned u = __builtin_bit_cast(unsigned, f);
    u += 0x7FFFu + ((u >> 16) & 1u);
    return (unsigned short)(u >> 16);
}

// barrier that waits only LDS ops (leaves global prefetch loads in flight)
__device__ __forceinline__ void bar_lgkm() {
    asm volatile("s_waitcnt lgkmcnt(0)" ::: "memory");
    __builtin_amdgcn_s_barrier();
}

// async global->LDS, 16B per lane; LDS dest must be wave-uniform base (+lane*16 implicit)
__device__ __forceinline__ void gld16(const unsigned short* g, unsigned short* l) {
    __builtin_amdgcn_global_load_lds((const __attribute__((address_space(1))) void*)g,
                                     (__attribute__((address_space(3))) void*)l, 16, 0, 0);
}

// ---------------- fp32 -> bf16 cast ----------------
__global__ __launch_bounds__(256) void cast_kernel(const float* __restrict__ in,
                                                   unsigned short* __restrict__ out, int n4) {
    int i = blockIdx.x * 256 + threadIdx.x;
    if (i < n4) {
        float4 v = reinterpret_cast<const float4*>(in)[i];
        ushort4 o;
        o.x = f2bf(v.x); o.y = f2bf(v.y); o.z = f2bf(v.z); o.w = f2bf(v.w);
        reinterpret_cast<ushort4*>(out)[i] = o;
    }
}

// ================= combined QKV projection (m97 structure) =================
__global__ __launch_bounds__(256) void gemm_qkv(const unsigned short* __restrict__ Qc,
                                                const unsigned short* __restrict__ Kc,
                                                const unsigned short* __restrict__ Vc,
                                                const unsigned short* __restrict__ Wqc,
                                                const unsigned short* __restrict__ Wkc,
                                                const unsigned short* __restrict__ Wvc,
                                                unsigned short* __restrict__ qh,
                                                unsigned short* __restrict__ kh,
                                                unsigned short* __restrict__ vT) {
    const int z = blockIdx.z;
    const unsigned short* A = (z == 0) ? Qc : (z == 1) ? Kc : Vc;
    const unsigned short* B = (z == 0) ? Wqc : (z == 1) ? Wkc : Wvc;
    const int tid = threadIdx.x, lane = tid & 63;
    const int l15 = lane & 15, lhi = lane >> 4;
    const int w = tid >> 6, wr = w >> 1, wc = w & 1;
    const int m0 = blockIdx.y * 128, n0 = blockIdx.x * 128;
    const int K = DM;
    const int lr8 = lane >> 3;             // row-in-8-row-group
    const int csw = (lane & 7) ^ lr8;      // swizzled 16B-chunk index (8 chunks/row)

    __shared__ unsigned short sA[128 * 64];
    __shared__ unsigned short sB[128 * 64];

    f32x4 acc[4][4];
#pragma unroll
    for (int i = 0; i < 4; ++i)
#pragma unroll
        for (int j = 0; j < 4; ++j) acc[i][j] = (f32x4){0.f, 0.f, 0.f, 0.f};

    for (int t = 0; t < 16; ++t) {
        const int k0 = t * 64;
#pragma unroll
        for (int i = 0; i < 4; ++i) {
            int g = w * 4 + i;
            int row = g * 8 + lr8;
            gld16(A + (size_t)(m0 + row) * K + k0 + csw * 8, sA + g * 512);
            gld16(B + (size_t)(n0 + row) * K + k0 + csw * 8, sB + g * 512);
        }
        __syncthreads();
#pragma unroll
        for (int kk = 0; kk < 2; ++kk) {
            bfrag a[4], b[4];
#pragma unroll
            for (int f = 0; f < 4; ++f) {
                int ra = wr * 64 + f * 16 + l15;
                a[f] = *reinterpret_cast<const bfrag*>(
                    sA + ra * 64 + (((kk * 4 + lhi) ^ (ra & 7)) << 3));
                int rb = wc * 64 + f * 16 + l15;
                b[f] = *reinterpret_cast<const bfrag*>(
                    sB + rb * 64 + (((kk * 4 + lhi) ^ (rb & 7)) << 3));
            }
#pragma unroll
            for (int fm = 0; fm < 4; ++fm)
#pragma unroll
                for (int fn = 0; fn < 4; ++fn)
                    acc[fm][fn] =
                        __builtin_amdgcn_mfma_f32_16x16x32_bf16(a[fm], b[fn], acc[fm][fn], 0, 0, 0);
        }
        __syncthreads();
    }

    if (z == 2) {
#pragma unroll
        for (int fm = 0; fm < 4; ++fm)
#pragma unroll
            for (int fn = 0; fn < 4; ++fn) {
                int sbase = m0 + wr * 64 + fm * 16 + (lhi << 2);
                int gcol = n0 + wc * 64 + fn * 16 + l15;
                int b = sbase >> 11, s = sbase & 2047, h = gcol >> 6, d = gcol & 63;
                ushort4 o;
                o.x = f2bf(acc[fm][fn][0]); o.y = f2bf(acc[fm][fn][1]);
                o.z = f2bf(acc[fm][fn][2]); o.w = f2bf(acc[fm][fn][3]);
                *reinterpret_cast<ushort4*>(vT + ((size_t)(b * NH + h) * DH + d) * S_LEN + s) = o;
            }
    } else {
        unsigned short* Out = (z == 0) ? qh : kh;
#pragma unroll
        for (int fm = 0; fm < 4; ++fm)
#pragma unroll
            for (int fn = 0; fn < 4; ++fn)
#pragma unroll
                for (int r = 0; r < 4; ++r) {
                    int grow = m0 + wr * 64 + fm * 16 + (lhi << 2) + r;
                    int gcol = n0 + wc * 64 + fn * 16 + l15;
                    int b = grow >> 11, s = grow & 2047, h = gcol >> 6, d = gcol & 63;
                    Out[((size_t)(b * NH + h) * S_LEN + s) * DH + d] = f2bf(acc[fm][fn][r]);
                }
    }
}

// ================= output projection =================
__global__ __launch_bounds__(256) void gemm_out(const unsigned short* __restrict__ A,
                                                const unsigned short* __restrict__ B,
                                                float* __restrict__ Out) {
    const int tid = threadIdx.x, lane = tid & 63;
    const int l15 = lane & 15, lhi = lane >> 4;
    const int w = tid >> 6, wr = w >> 1, wc = w & 1;
    const int m0 = blockIdx.y * 128, n0 = blockIdx.x * 128;
    const int K = DM, N = DM;
    const int lr8 = lane >> 3;
    const int csw = (lane & 7) ^ lr8;

    __shared__ unsigned short sA[128 * 64];
    __shared__ unsigned short sB[128 * 64];

    f32x4 acc[4][4];
#pragma unroll
    for (int i = 0; i < 4; ++i)
#pragma unroll
        for (int j = 0; j < 4; ++j) acc[i][j] = (f32x4){0.f, 0.f, 0.f, 0.f};

    for (int t = 0; t < 16; ++t) {
        const int k0 = t * 64;
#pragma unroll
        for (int i = 0; i < 4; ++i) {
            int g = w * 4 + i;
            int row = g * 8 + lr8;
            gld16(A + (size_t)(m0 + row) * K + k0 + csw * 8, sA + g * 512);
            gld16(B + (size_t)(n0 + row) * K + k0 + csw * 8, sB + g * 512);
        }
        __syncthreads();
#pragma unroll
        for (int kk = 0; kk < 2; ++kk) {
            bfrag a[4], b[4];
#pragma unroll
            for (int f = 0; f < 4; ++f) {
                int ra = wr * 64 + f * 16 + l15;
                a[f] = *reinterpret_cast<const bfrag*>(
                    sA + ra * 64 + (((kk * 4 + lhi) ^ (ra & 7)) << 3));
                int rb = wc * 64 + f * 16 + l15;
                b[f] = *reinterpret_cast<const bfrag*>(
                    sB + rb * 64 + (((kk * 4 + lhi) ^ (rb & 7)) << 3));
            }
#pragma unroll
            for (int fm = 0; fm < 4; ++fm)
#pragma unroll
                for (int fn = 0; fn < 4; ++fn)
                    acc[fm][fn] =
                        __builtin_amdgcn_mfma_f32_16x16x32_bf16(a[fm], b[fn], acc[fm][fn], 0, 0, 0);
        }
        __syncthreads();
    }

#pragma unroll
    for (int fm = 0; fm < 4; ++fm)
#pragma unroll
        for (int fn = 0; fn < 4; ++fn)
#pragma unroll
            for (int r = 0; r < 4; ++r) {
                int grow = m0 + wr * 64 + fm * 16 + (lhi << 2) + r;
                int gcol = n0 + wc * 64 + fn * 16 + l15;
                Out[(size_t)grow * N + gcol] = acc[fm][fn][r];
            }
}

// ================= fused scores + softmax + PV (swapped-operand, vectorized) =================
// Block = one (b,h), one 64-row Q strip. Wave w owns q-rows w*16..w*16+15 (q = lane&15).
// Swapped MFMA: S^T frag -> each lane holds ONE q-row, 4 consecutive k per fragment ->
// all prev/scores/attn traffic is float4 per lane. Softmax reduce = shfl_xor 16,32.
__global__ __launch_bounds__(256, 4) void attn_fused(const unsigned short* __restrict__ qh,
                                                     const unsigned short* __restrict__ kh,
                                                     const unsigned short* __restrict__ vT,
                                                     const float* __restrict__ prev,
                                                     float* __restrict__ scores,
                                                     float* __restrict__ attn,
                                                     unsigned short* __restrict__ ctx) {
    const int z = blockIdx.z;         // b*NH + h
    const int m0 = blockIdx.x * 64;   // Q strip base
    const int tid = threadIdx.x;
    const int lane = tid & 63;
    const int w = tid >> 6;
    const int l15 = lane & 15, lhi = lane >> 4;

    __shared__ unsigned short smem[16384];     // 32 KB
    unsigned short* sQ = smem;                 // [64][64]  phase 1
    unsigned short* sK = smem + 4096;          // [128][64] phase 1
    unsigned short* sV = smem;                 // [64][128] phase 2
    unsigned short* sP = smem + 8192;          // [64][128] phase 2

    const unsigned short* Qz = qh + (size_t)z * S_LEN * DH;
    const unsigned short* Kz = kh + (size_t)z * S_LEN * DH;
    const unsigned short* Vz = vT + (size_t)z * DH * S_LEN;
    const size_t zbase = (size_t)z * S_LEN * S_LEN;
    const float scale = 0.125f;  // 1/sqrt(64)

    const int qrow = w * 16 + l15;                    // local q row this lane owns
    const float* prevRow = prev + zbase + (size_t)(m0 + qrow) * S_LEN;
    float* scoresRow = scores + zbase + (size_t)(m0 + qrow) * S_LEN;
    float* attnRow = attn + zbase + (size_t)(m0 + qrow) * S_LEN;
    const int c4 = lhi * 4;                           // col offset within 16-group

    // stage Q strip
#pragma unroll
    for (int i = 0; i < 2; ++i) {
        int c = i * 256 + tid, row = c >> 3, col8 = c & 7;
        *reinterpret_cast<int4*>(sQ + row * 64 + ((col8 * 8) ^ ((row & 7) * 8))) =
            *reinterpret_cast<const int4*>(Qz + (size_t)(m0 + row) * DH + col8 * 8);
    }

    float m_r = -1e30f, l_r = 0.f;

    // prologue: tile-0 K + prev
    int4 kreg[4];
#pragma unroll
    for (int i = 0; i < 4; ++i) {
        int c = i * 256 + tid, row = c >> 3, col8 = c & 7;
        kreg[i] = *reinterpret_cast<const int4*>(Kz + (size_t)row * DH + col8 * 8);
    }
    f32x4 pv4[8];
#pragma unroll
    for (int fn = 0; fn < 8; ++fn)
        pv4[fn] = __builtin_nontemporal_load(
            reinterpret_cast<const f32x4*>(prevRow + fn * 16 + c4));

    // ---------- phase 1 ----------
    for (int kt = 0; kt < S_LEN / 128; ++kt) {
        const int n0 = kt * 128;
        bar_lgkm();  // prior MFMA ds_reads of sK complete everywhere
#pragma unroll
        for (int i = 0; i < 4; ++i) {
            int c = i * 256 + tid, row = c >> 3, col8 = c & 7;
            *reinterpret_cast<int4*>(sK + row * 64 + ((col8 * 8) ^ ((row & 7) * 8))) = kreg[i];
        }
        if (kt < 15) {
            const int n1 = n0 + 128;
#pragma unroll
            for (int i = 0; i < 4; ++i) {
                int c = i * 256 + tid, row = c >> 3, col8 = c & 7;
                kreg[i] = *reinterpret_cast<const int4*>(Kz + (size_t)(n1 + row) * DH + col8 * 8);
            }
        }
        bar_lgkm();  // sK visible

        f32x4 acc[8];
#pragma unroll
        for (int fn = 0; fn < 8; ++fn) acc[fn] = (f32x4){0.f, 0.f, 0.f, 0.f};
#pragma unroll
        for (int kk = 0; kk < 2; ++kk) {
            bfrag qf = *reinterpret_cast<const bfrag*>(
                sQ + qrow * 64 + (((kk * 4 + lhi) ^ (qrow & 7)) << 3));
            bfrag kf[8];
#pragma unroll
            for (int f = 0; f < 8; ++f) {
                int rb = f * 16 + l15;
                kf[f] = *reinterpret_cast<const bfrag*>(
                    sK + rb * 64 + (((kk * 4 + lhi) ^ (rb & 7)) << 3));
            }
#pragma unroll
            for (int fn = 0; fn < 8; ++fn)
                acc[fn] = __builtin_amdgcn_mfma_f32_16x16x32_bf16(kf[fn], qf, acc[fn], 0, 0, 0);
        }

        // consume prev -> s; refill prev(t+1); store scores (float4)
#pragma unroll
        for (int fn = 0; fn < 8; ++fn)
#pragma unroll
            for (int r = 0; r < 4; ++r) acc[fn][r] = acc[fn][r] * scale + pv4[fn][r];
        if (kt < 15) {
            const int n1 = n0 + 128;
#pragma unroll
            for (int fn = 0; fn < 8; ++fn)
                pv4[fn] = __builtin_nontemporal_load(
                    reinterpret_cast<const f32x4*>(prevRow + n1 + fn * 16 + c4));
        }
#pragma unroll
        for (int fn = 0; fn < 8; ++fn)
            *reinterpret_cast<f32x4*>(scoresRow + n0 + fn * 16 + c4) = acc[fn];

        // online softmax (row owned by 4 lanes: this, ^16, ^32)
        float pm = acc[0][0];
#pragma unroll
        for (int fn = 0; fn < 8; ++fn)
#pragma unroll
            for (int r = 0; r < 4; ++r) pm = fmaxf(pm, acc[fn][r]);
        pm = fmaxf(pm, __shfl_xor(pm, 16));
        pm = fmaxf(pm, __shfl_xor(pm, 32));
        float mnew = fmaxf(m_r, pm);
        float psum = 0.f;
#pragma unroll
        for (int fn = 0; fn < 8; ++fn)
#pragma unroll
            for (int r = 0; r < 4; ++r) psum += __expf(acc[fn][r] - mnew);
        psum += __shfl_xor(psum, 16);
        psum += __shfl_xor(psum, 32);
        l_r = l_r * __expf(m_r - mnew) + psum;
        m_r = mnew;
    }

    const float inv_l = 1.0f / l_r;

    // ---------- phase 2 (reverse tile order: hottest scores first) ----------
    f32x4 acco[4];
#pragma unroll
    for (int fn = 0; fn < 4; ++fn) acco[fn] = (f32x4){0.f, 0.f, 0.f, 0.f};

    int4 vreg[4];
#pragma unroll
    for (int i = 0; i < 4; ++i) {
        int c = i * 256 + tid, row = c >> 4, col8 = c & 15;
        vreg[i] = *reinterpret_cast<const int4*>(Vz + (size_t)row * S_LEN + 15 * 128 + col8 * 8);
    }
    f32x4 sv4[8];
#pragma unroll
    for (int fn = 0; fn < 8; ++fn)
        sv4[fn] = *reinterpret_cast<const f32x4*>(scoresRow + 15 * 128 + fn * 16 + c4);

    for (int kt = 15; kt >= 0; --kt) {
        const int n0 = kt * 128;
        bar_lgkm();  // prior MFMA ds_reads of sV/sP complete (covers phase-1 tail first iter)
#pragma unroll
        for (int i = 0; i < 4; ++i) {
            int c = i * 256 + tid, row = c >> 4, col8 = c & 15;
            *reinterpret_cast<int4*>(sV + row * 128 + ((col8 ^ (row & 7)) << 3)) = vreg[i];
        }
        if (kt > 0) {
            const int n1 = n0 - 128;
#pragma unroll
            for (int i = 0; i < 4; ++i) {
                int c = i * 256 + tid, row = c >> 4, col8 = c & 15;
                vreg[i] = *reinterpret_cast<const int4*>(Vz + (size_t)row * S_LEN + n1 + col8 * 8);
            }
        }
        // p = exp(s-m)/l: write attn (NT float4), stage p into sP (8B ds_write)
#pragma unroll
        for (int fn = 0; fn < 8; ++fn) {
            f32x4 p4;
#pragma unroll
            for (int r = 0; r < 4; ++r) p4[r] = __expf(sv4[fn][r] - m_r) * inv_l;
            __builtin_nontemporal_store(p4,
                                        reinterpret_cast<f32x4*>(attnRow + n0 + fn * 16 + c4));
            ushort4 pb;
            pb.x = f2bf(p4[0]); pb.y = f2bf(p4[1]); pb.z = f2bf(p4[2]); pb.w = f2bf(p4[3]);
            int cch = (fn * 2 + (lhi >> 1)) ^ (qrow & 7);
            *reinterpret_cast<ushort4*>(sP + qrow * 128 + cch * 8 + (lhi & 1) * 4) = pb;
        }
        if (kt > 0) {
            const int n1 = n0 - 128;
#pragma unroll
            for (int fn = 0; fn < 8; ++fn)
                sv4[fn] = *reinterpret_cast<const f32x4*>(scoresRow + n1 + fn * 16 + c4);
        }
        bar_lgkm();  // sV/sP visible
        // O^T += V^T @ P^T
#pragma unroll
        for (int kk = 0; kk < 4; ++kk) {
            bfrag pf = *reinterpret_cast<const bfrag*>(
                sP + qrow * 128 + (((kk * 4 + lhi) ^ (qrow & 7)) << 3));
            bfrag vf[4];
#pragma unroll
            for (int f = 0; f < 4; ++f) {
                int rv = f * 16 + l15;
                vf[f] = *reinterpret_cast<const bfrag*>(
                    sV + rv * 128 + (((kk * 4 + lhi) ^ (rv & 7)) << 3));
            }
#pragma unroll
            for (int fn = 0; fn < 4; ++fn)
                acco[fn] = __builtin_amdgcn_mfma_f32_16x16x32_bf16(vf[fn], pf, acco[fn], 0, 0, 0);
        }
    }

    // write ctx (b, s, h*DH + d) bf16; lane owns q-row, 4 consecutive d per fn
    const int b = z >> 4, h = z & 15;
    const int s = m0 + qrow;
#pragma unroll
    for (int fn = 0; fn < 4; ++fn) {
        int d0 = fn * 16 + c4;
        ushort4 o;
        o.x = f2bf(acco[fn][0]); o.y = f2bf(acco[fn][1]);
        o.z = f2bf(acco[fn][2]); o.w = f2bf(acco[fn][3]);
        *reinterpret_cast<ushort4*>(ctx + ((size_t)(b * S_LEN + s)) * DM + h * DH + d0) = o;
    }
}

extern "C" void kernel_launch(void* const* d_in, const int* in_sizes, int n_in, void* d_out,
                              int out_size, void* d_ws, size_t ws_size, hipStream_t stream) {
    const float* Q = (const float*)d_in[0];
    const float* K = (const float*)d_in[1];
    const float* V = (const float*)d_in[2];
    const float* prev = (const float*)d_in[3];
    const float* Wq = (const float*)d_in[4];
    const float* Wk = (const float*)d_in[5];
    const float* Wv = (const float*)d_in[6];
    const float* Wo = (const float*)d_in[7];

    float* out = (float*)d_out;
    float* attn = out + (size_t)BS * DM;
    float* scores = attn + (size_t)NB * NH * S_LEN * S_LEN;

    unsigned short* ws = (unsigned short*)d_ws;
    unsigned short* Qc = ws;
    unsigned short* Kc = Qc + (size_t)BS * DM;
    unsigned short* Vc = Kc + (size_t)BS * DM;
    unsigned short* Wqc = Vc + (size_t)BS * DM;
    unsigned short* Wkc = Wqc + (size_t)DM * DM;
    unsigned short* Wvc = Wkc + (size_t)DM * DM;
    unsigned short* Woc = Wvc + (size_t)DM * DM;
    unsigned short* qh = Woc + (size_t)DM * DM;    // (b,h,s,d) bf16
    unsigned short* kh = qh + (size_t)BS * DM;     // (b,h,s,d) bf16
    unsigned short* vT = kh + (size_t)BS * DM;     // (b,h,d,s) bf16
    unsigned short* ctx = vT + (size_t)BS * DM;    // (b,s,h*d) bf16

    // casts
    cast_kernel<<<BS * DM / 4 / 256, 256, 0, stream>>>(Q, Qc, BS * DM / 4);
    cast_kernel<<<BS * DM / 4 / 256, 256, 0, stream>>>(K, Kc, BS * DM / 4);
    cast_kernel<<<BS * DM / 4 / 256, 256, 0, stream>>>(V, Vc, BS * DM / 4);
    cast_kernel<<<DM * DM / 4 / 256, 256, 0, stream>>>(Wq, Wqc, DM * DM / 4);
    cast_kernel<<<DM * DM / 4 / 256, 256, 0, stream>>>(Wk, Wkc, DM * DM / 4);
    cast_kernel<<<DM * DM / 4 / 256, 256, 0, stream>>>(Wv, Wvc, DM * DM / 4);
    cast_kernel<<<DM * DM / 4 / 256, 256, 0, stream>>>(Wo, Woc, DM * DM / 4);

    // combined QKV projections (768 blocks)
    dim3 gq(DM / 128, BS / 128, 3);
    gemm_qkv<<<gq, 256, 0, stream>>>(Qc, Kc, Vc, Wqc, Wkc, Wvc, qh, kh, vT);

    // fused scores + softmax + PV (1024 blocks)
    dim3 ga(S_LEN / 64, 1, NB * NH);
    attn_fused<<<ga, 256, 0, stream>>>(qh, kh, vT, prev, scores, attn, ctx);

    // output projection (256 blocks)
    dim3 gp(DM / 128, BS / 128, 1);
    gemm_out<<<gp, 256, 0, stream>>>(ctx, Woc, out);
}